// Round 2
// baseline (575.720 us; speedup 1.0000x reference)
//
#include <hip/hip_runtime.h>
#include <math.h>

#define EPSF 1.1920928955078125e-07f  // np.float32 eps

constexpr int B_ = 16, S_ = 8, CH = 3, K_ = 6;
constexpr int P_ = 128 * 128;   // pixels per image
constexpr int NCH = 32;         // chunks per image
constexpr int CPIX = P_ / NCH;  // 512 pixels per chunk
constexpr int TILE = 128;       // LDS staging tile (pixels)
constexpr int STRD = 28;        // padded LDS stride (27 channels + 1 pad, 16B-aligned rows)
constexpr int NF1 = 106;        // per-k moments: 96 ops_first + 10 sym M2
constexpr int NF2 = 48;         // per-k sigma sums: 8 s * 6 sym

// ------------------------------------------------------------------ staging
template <int NT>
__device__ __forceinline__ void stage27(const float* __restrict__ imgu,
                                        const float* __restrict__ shfu, int tp0,
                                        float* __restrict__ stg, int tid) {
  for (int e = tid; e < 27 * TILE; e += NT) {
    int c = e >> 7, pix = e & (TILE - 1);
    stg[pix * STRD + c] = (c < CH) ? imgu[c * P_ + tp0 + pix]
                                   : shfu[(c - CH) * P_ + tp0 + pix];
  }
}

// per-pixel vector load: img channels + this wave's 12 shifted channels
template <int S0>
__device__ __forceinline__ void loadpix(const float* Lp, float& i0, float& i1,
                                        float& i2, float (&sh)[12]) {
  const float4* v = (const float4*)Lp;
  float4 a0 = v[0];
  i0 = a0.x; i1 = a0.y; i2 = a0.z;
  if constexpr (S0 == 0) {  // channels 3..14
    float4 a1 = v[1], a2 = v[2], a3 = v[3];
    sh[0] = a0.w; sh[1] = a1.x; sh[2] = a1.y; sh[3] = a1.z; sh[4] = a1.w;
    sh[5] = a2.x; sh[6] = a2.y; sh[7] = a2.z; sh[8] = a2.w;
    sh[9] = a3.x; sh[10] = a3.y; sh[11] = a3.z;
  } else {  // channels 15..26
    float4 a3 = v[3], a4 = v[4], a5 = v[5], a6 = v[6];
    sh[0] = a3.w; sh[1] = a4.x; sh[2] = a4.y; sh[3] = a4.z; sh[4] = a4.w;
    sh[5] = a5.x; sh[6] = a5.y; sh[7] = a5.z; sh[8] = a5.w;
    sh[9] = a6.x; sh[10] = a6.y; sh[11] = a6.z;
  }
}

// ------------------------------------------------------------------ 4x4 inverse
__device__ __forceinline__ void inv4(const float* Ain, float* out) {
  float a[4][8];
#pragma unroll
  for (int i = 0; i < 4; i++) {
#pragma unroll
    for (int j = 0; j < 4; j++) { a[i][j] = Ain[i * 4 + j]; a[i][4 + j] = (i == j) ? 1.f : 0.f; }
  }
#pragma unroll
  for (int c = 0; c < 4; c++) {
    float piv = 1.f / a[c][c];
#pragma unroll
    for (int j = 0; j < 8; j++) a[c][j] *= piv;
#pragma unroll
    for (int r = 0; r < 4; r++) {
      if (r != c) {
        float f = a[r][c];
#pragma unroll
        for (int j = 0; j < 8; j++) a[r][j] -= f * a[c][j];
      }
    }
  }
#pragma unroll
  for (int i = 0; i < 4; i++)
#pragma unroll
    for (int j = 0; j < 4; j++) out[i * 4 + j] = a[i][4 + j];
}

// ------------------------------------------------------------------ softmax (step 0)
__global__ __launch_bounds__(256) void k_softmax0(const float* __restrict__ pred,
                                                  float* __restrict__ gp) {
  int g = blockIdx.x * 256 + threadIdx.x;
  int u = g >> 14, p = g & (P_ - 1);
  const float* pr = pred + ((size_t)u * K_) * P_ + p;
  float l[K_];
  float mx = -1e30f;
#pragma unroll
  for (int k = 0; k < K_; k++) { l[k] = pr[(size_t)k * P_]; mx = fmaxf(mx, l[k]); }
  float s = 0.f;
#pragma unroll
  for (int k = 0; k < K_; k++) { l[k] = expf(l[k] - mx); s += l[k]; }
  float inv = 1.f / s;
  float* gw = gp + ((size_t)u * K_) * P_ + p;
#pragma unroll
  for (int k = 0; k < K_; k++) gw[(size_t)k * P_] = l[k] * inv + EPSF;
}

// ------------------------------------------------------------------ reduce1 body
template <int S0>
__device__ __forceinline__ void r1_body(const float* __restrict__ stg,
                                        const float* __restrict__ gpt,
                                        float (&acc)[58], int lane) {
#pragma unroll
  for (int rep = 0; rep < 2; rep++) {
    int pix = lane + rep * 64;
    float i0, i1, i2, sh[12];
    loadpix<S0>(&stg[pix * STRD], i0, i1, i2, sh);
    float gpv = gpt[pix];
    float t0 = gpv * i0, t1 = gpv * i1, t2 = gpv * i2;
#pragma unroll
    for (int sa = 0; sa < 12; sa++) {
      float svv = sh[sa];
      acc[sa * 4 + 0] += svv * t0;
      acc[sa * 4 + 1] += svv * t1;
      acc[sa * 4 + 2] += svv * t2;
      acc[sa * 4 + 3] += svv * gpv;
    }
    if constexpr (S0 == 0) {  // symmetric M2 (only one s-half needs it)
      acc[48] += i0 * t0; acc[49] += i0 * t1; acc[50] += i0 * t2; acc[51] += t0;
      acc[52] += i1 * t1; acc[53] += i1 * t2; acc[54] += t1;
      acc[55] += i2 * t2; acc[56] += t2;      acc[57] += gpv;
    }
  }
}

// ------------------------------------------------------------------ reduce1
// grid = B*NCH*2 (kgroup), block = 384 = 6 waves = (3 k) x (2 s-halves)
__global__ __launch_bounds__(384) void k_reduce1(const float* __restrict__ img,
                                                 const float* __restrict__ shf,
                                                 const float* __restrict__ gp,
                                                 float* __restrict__ p1) {
  __shared__ __align__(16) float stg[TILE * STRD];
  __shared__ float red[6 * 58 * 9];
  int bid = blockIdx.x;
  int u = bid >> 6, ch = (bid >> 1) & 31, kg = bid & 1;
  int tid = threadIdx.x, w = tid >> 6, lane = tid & 63;
  int k = kg * 3 + (w >> 1), shalf = w & 1;

  const float* imgu = img + (size_t)u * CH * P_;
  const float* shfu = shf + (size_t)u * S_ * CH * P_;
  const float* gpu = gp + (size_t)(u * K_ + k) * P_;

  float acc[58];
#pragma unroll
  for (int i = 0; i < 58; i++) acc[i] = 0.f;

  for (int t = 0; t < CPIX / TILE; t++) {
    int tp0 = ch * CPIX + t * TILE;
    stage27<384>(imgu, shfu, tp0, stg, tid);
    __syncthreads();
    if (shalf == 0) r1_body<0>(stg, gpu + tp0, acc, lane);
    else            r1_body<4>(stg, gpu + tp0, acc, lane);
    __syncthreads();
  }
  // 3-step shuffle (8-lane groups), then LDS transpose + per-lane column sums
#pragma unroll
  for (int j = 0; j < 48; j++) {
    float v = acc[j];
    v += __shfl_xor(v, 1, 64); v += __shfl_xor(v, 2, 64); v += __shfl_xor(v, 4, 64);
    acc[j] = v;
  }
  if (shalf == 0) {
#pragma unroll
    for (int j = 48; j < 58; j++) {
      float v = acc[j];
      v += __shfl_xor(v, 1, 64); v += __shfl_xor(v, 2, 64); v += __shfl_xor(v, 4, 64);
      acc[j] = v;
    }
  }
  int l8 = lane >> 3;
  if ((lane & 7) == 0) {
#pragma unroll
    for (int j = 0; j < 48; j++) red[(w * 58 + j) * 9 + l8] = acc[j];
    if (shalf == 0) {
#pragma unroll
      for (int j = 48; j < 58; j++) red[(w * 58 + j) * 9 + l8] = acc[j];
    }
  }
  __syncthreads();
  int nv = (shalf == 0) ? 58 : 48;
  if (lane < nv) {
    float s = 0.f;
#pragma unroll
    for (int i = 0; i < 8; i++) s += red[(w * 58 + lane) * 9 + i];
    int off = (shalf == 0) ? ((lane < 48) ? lane : 96 + (lane - 48)) : 48 + lane;
    p1[((size_t)(u * K_ + k) * NCH + ch) * NF1 + off] = s;
  }
}

// ------------------------------------------------------------------ reduce2 body
template <int S0>
__device__ __forceinline__ void r2_body(const float* __restrict__ stg,
                                        const float* __restrict__ gpt, float pn,
                                        const float (&opr)[48], float (&acc)[24],
                                        int lane) {
#pragma unroll
  for (int rep = 0; rep < 2; rep++) {
    int pix = lane + rep * 64;
    float i0, i1, i2, sh[12];
    loadpix<S0>(&stg[pix * STRD], i0, i1, i2, sh);
    float pp = gpt[pix] * pn;
#pragma unroll
    for (int sl = 0; sl < 4; sl++) {
      const float* o = &opr[sl * 12];
      float d0 = sh[sl * 3 + 0] - (o[0] * i0 + o[1] * i1 + o[2] * i2 + o[3]);
      float d1 = sh[sl * 3 + 1] - (o[4] * i0 + o[5] * i1 + o[6] * i2 + o[7]);
      float d2 = sh[sl * 3 + 2] - (o[8] * i0 + o[9] * i1 + o[10] * i2 + o[11]);
      float q0 = pp * d0, q1 = pp * d1, q2 = pp * d2;
      acc[sl * 6 + 0] += q0 * d0; acc[sl * 6 + 1] += q0 * d1; acc[sl * 6 + 2] += q0 * d2;
      acc[sl * 6 + 3] += q1 * d1; acc[sl * 6 + 4] += q1 * d2; acc[sl * 6 + 5] += q2 * d2;
    }
  }
}

// ------------------------------------------------------------------ reduce2
__global__ __launch_bounds__(384) void k_reduce2(const float* __restrict__ img,
                                                 const float* __restrict__ shf,
                                                 const float* __restrict__ gp,
                                                 const float* __restrict__ p1,
                                                 float* __restrict__ p2) {
  __shared__ __align__(16) float stg[TILE * STRD];
  __shared__ float sum1[3 * NF1];
  __shared__ float invA[3 * 16];
  __shared__ float normL[3], pnL[3];
  __shared__ float opsL[3 * 96];
  __shared__ float red[6 * 24 * 9];
  int bid = blockIdx.x;
  int u = bid >> 6, ch = (bid >> 1) & 31, kg = bid & 1;
  int tid = threadIdx.x, w = tid >> 6, lane = tid & 63;
  int k3 = w >> 1, k = kg * 3 + k3, shalf = w & 1;

  for (int e = tid; e < 3 * NF1; e += 384) {
    int kk = e / NF1, i = e % NF1;
    const float* src = p1 + ((size_t)(u * K_ + kg * 3 + kk) * NCH) * NF1 + i;
    float s = 0.f;
#pragma unroll
    for (int c2 = 0; c2 < NCH; c2++) s += src[(size_t)c2 * NF1];
    sum1[e] = s;
  }
  __syncthreads();
  if (tid < 3) {
    const float* m = &sum1[tid * NF1 + 96];
    float tr = m[0] + m[4] + m[7] + m[9];
    float nrm = 1.f / tr;
    normL[tid] = nrm;
    pnL[tid] = 1.f / m[9];
    const int sym[4][4] = {{0, 1, 2, 3}, {1, 4, 5, 6}, {2, 5, 7, 8}, {3, 6, 8, 9}};
    float A[16];
#pragma unroll
    for (int i = 0; i < 4; i++)
#pragma unroll
      for (int j = 0; j < 4; j++)
        A[i * 4 + j] = m[sym[i][j]] * nrm + ((i == j) ? EPSF : 0.f);
    inv4(A, &invA[tid * 16]);
  }
  __syncthreads();
  for (int e = tid; e < 3 * 96; e += 384) {
    int kk = e / 96, r = e % 96, sa = r >> 2, bc = r & 3;
    float v = 0.f;
#pragma unroll
    for (int c = 0; c < 4; c++) v += sum1[kk * NF1 + sa * 4 + c] * invA[kk * 16 + c * 4 + bc];
    opsL[e] = v * normL[kk];
  }
  __syncthreads();

  float opr[48];
#pragma unroll
  for (int j = 0; j < 48; j++) opr[j] = opsL[k3 * 96 + shalf * 48 + j];
  float pn = pnL[k3];
  const float* imgu = img + (size_t)u * CH * P_;
  const float* shfu = shf + (size_t)u * S_ * CH * P_;
  const float* gpu = gp + (size_t)(u * K_ + k) * P_;

  float acc[24];
#pragma unroll
  for (int j = 0; j < 24; j++) acc[j] = 0.f;

  for (int t = 0; t < CPIX / TILE; t++) {
    int tp0 = ch * CPIX + t * TILE;
    stage27<384>(imgu, shfu, tp0, stg, tid);
    __syncthreads();
    if (shalf == 0) r2_body<0>(stg, gpu + tp0, pn, opr, acc, lane);
    else            r2_body<4>(stg, gpu + tp0, pn, opr, acc, lane);
    __syncthreads();
  }
#pragma unroll
  for (int j = 0; j < 24; j++) {
    float v = acc[j];
    v += __shfl_xor(v, 1, 64); v += __shfl_xor(v, 2, 64); v += __shfl_xor(v, 4, 64);
    acc[j] = v;
  }
  int l8 = lane >> 3;
  if ((lane & 7) == 0) {
#pragma unroll
    for (int j = 0; j < 24; j++) red[(w * 24 + j) * 9 + l8] = acc[j];
  }
  __syncthreads();
  if (lane < 24) {
    float s = 0.f;
#pragma unroll
    for (int i = 0; i < 8; i++) s += red[(w * 24 + lane) * 9 + i];
    p2[((size_t)(u * K_ + k) * NCH + ch) * NF2 + shalf * 24 + lane] = s;
  }
}

// ------------------------------------------------------------------ e-step body
template <int S0>
__device__ __forceinline__ void estep_body(const float* __restrict__ stg,
                                           const float (&opr)[48], const float (&sv)[24],
                                           int lane, int k, int shalf,
                                           float* __restrict__ qL, float (&qp)[2]) {
#pragma unroll
  for (int rep = 0; rep < 2; rep++) {
    int pix = lane + rep * 64;
    float i0, i1, i2, sh[12];
    loadpix<S0>(&stg[pix * STRD], i0, i1, i2, sh);
    float q = 0.f;
#pragma unroll
    for (int sl = 0; sl < 4; sl++) {
      const float* o = &opr[sl * 12];
      float d0 = sh[sl * 3 + 0] - (o[0] * i0 + o[1] * i1 + o[2] * i2 + o[3]);
      float d1 = sh[sl * 3 + 1] - (o[4] * i0 + o[5] * i1 + o[6] * i2 + o[7]);
      float d2 = sh[sl * 3 + 2] - (o[8] * i0 + o[9] * i1 + o[10] * i2 + o[11]);
      const float* si = &sv[sl * 6];
      q += si[0] * d0 * d0 + si[3] * d1 * d1 + si[5] * d2 * d2 +
           si[1] * d0 * d1 + si[2] * d0 * d2 + si[4] * d1 * d2;
    }
    qp[rep] = q;
    if (shalf) qL[k * TILE + pix] = q;
  }
}

// ------------------------------------------------------------------ e-step (+ fused softmax)
// grid = B*NCH, block = 768 = 12 waves = (6 k) x (2 s-halves)
template <int LAST>
__global__ __launch_bounds__(768) void k_estep(const float* __restrict__ img,
                                               const float* __restrict__ shf,
                                               const float* __restrict__ pred,
                                               const float* __restrict__ p1,
                                               const float* __restrict__ p2,
                                               float* __restrict__ out,
                                               float* __restrict__ gp) {
  __shared__ __align__(16) float stg[TILE * STRD];
  __shared__ float qL[K_ * TILE];
  __shared__ float gmL[TILE * K_];
  __shared__ float sum1[K_ * NF1];
  __shared__ float sum2[K_ * NF2];
  __shared__ float invA[K_ * 16];
  __shared__ float normL[K_];
  __shared__ float opsL[K_ * 96];
  __shared__ float sinvL[K_ * S_ * 6];
  __shared__ float ldetL[K_ * S_];
  __shared__ float ldhL[K_];

  int bid = blockIdx.x;
  int u = bid >> 5, ch = bid & 31;
  int tid = threadIdx.x, w = tid >> 6, lane = tid & 63;
  int k = w >> 1, shalf = w & 1;

  for (int e = tid; e < K_ * NF1; e += 768) {
    int kk = e / NF1, i = e % NF1;
    const float* src = p1 + ((size_t)(u * K_ + kk) * NCH) * NF1 + i;
    float s = 0.f;
#pragma unroll
    for (int c2 = 0; c2 < NCH; c2++) s += src[(size_t)c2 * NF1];
    sum1[e] = s;
  }
  for (int e = tid; e < K_ * NF2; e += 768) {
    int kk = e / NF2, j = e % NF2;
    const float* src = p2 + ((size_t)(u * K_ + kk) * NCH) * NF2 + j;
    float s = 0.f;
#pragma unroll
    for (int c2 = 0; c2 < NCH; c2++) s += src[(size_t)c2 * NF2];
    sum2[e] = s;
  }
  __syncthreads();
  if (tid < K_) {
    const float* m = &sum1[tid * NF1 + 96];
    float tr = m[0] + m[4] + m[7] + m[9];
    float nrm = 1.f / tr;
    normL[tid] = nrm;
    const int sym[4][4] = {{0, 1, 2, 3}, {1, 4, 5, 6}, {2, 5, 7, 8}, {3, 6, 8, 9}};
    float A[16];
#pragma unroll
    for (int i = 0; i < 4; i++)
#pragma unroll
      for (int j = 0; j < 4; j++)
        A[i * 4 + j] = m[sym[i][j]] * nrm + ((i == j) ? EPSF : 0.f);
    inv4(A, &invA[tid * 16]);
  } else if (tid >= 64 && tid < 64 + K_ * S_) {
    int t2 = tid - 64;  // k*8+s
    int base = (t2 >> 3) * NF2 + (t2 & 7) * 6;
    float a = sum2[base + 0] + EPSF, b = sum2[base + 1], c = sum2[base + 2];
    float d = sum2[base + 3] + EPSF, e2 = sum2[base + 4], f = sum2[base + 5] + EPSF;
    float c00 = d * f - e2 * e2, c01 = c * e2 - b * f, c02 = b * e2 - c * d;
    float det = a * c00 + b * c01 + c * c02;
    float id = 1.f / det;
    // pre-scale: 0.5*quad folded in (off-diagonals carry the 2x factor)
    sinvL[t2 * 6 + 0] = 0.5f * c00 * id;
    sinvL[t2 * 6 + 1] = c01 * id;
    sinvL[t2 * 6 + 2] = c02 * id;
    sinvL[t2 * 6 + 3] = 0.5f * (a * f - c * c) * id;
    sinvL[t2 * 6 + 4] = (c * b - a * e2) * id;
    sinvL[t2 * 6 + 5] = 0.5f * (a * d - b * b) * id;
    ldetL[t2] = logf(det);
  }
  __syncthreads();
  for (int e = tid; e < K_ * 96; e += 768) {
    int kk = e / 96, r = e % 96, sa = r >> 2, bc = r & 3;
    float v = 0.f;
#pragma unroll
    for (int c = 0; c < 4; c++) v += sum1[kk * NF1 + sa * 4 + c] * invA[kk * 16 + c * 4 + bc];
    opsL[e] = v * normL[kk];
  }
  if (tid < K_) {
    float s = 0.f;
#pragma unroll
    for (int si = 0; si < S_; si++) s += ldetL[tid * S_ + si];
    ldhL[tid] = 0.5f * s;
  }
  __syncthreads();

  float opr[48];
#pragma unroll
  for (int j = 0; j < 48; j++) opr[j] = opsL[k * 96 + shalf * 48 + j];
  float sv[24];
#pragma unroll
  for (int j = 0; j < 24; j++) sv[j] = sinvL[(k * S_ + shalf * 4) * 6 + j];
  float ldh = ldhL[k];

  const float* imgu = img + (size_t)u * CH * P_;
  const float* shfu = shf + (size_t)u * S_ * CH * P_;
  const float* predu = pred + (size_t)u * K_ * P_;
  float* outu = out + (size_t)u * K_ * P_;
  float* gpu = gp + (size_t)u * K_ * P_;

  for (int t = 0; t < CPIX / TILE; t++) {
    int tp0 = ch * CPIX + t * TILE;
    stage27<768>(imgu, shfu, tp0, stg, tid);
    __syncthreads();
    float qp[2];
    if (shalf == 0) estep_body<0>(stg, opr, sv, lane, k, 0, qL, qp);
    else            estep_body<4>(stg, opr, sv, lane, k, 1, qL, qp);
    __syncthreads();
    if (shalf == 0) {
#pragma unroll
      for (int rep = 0; rep < 2; rep++) {
        int pix = lane + rep * 64;
        float gm = -(qp[rep] + qL[k * TILE + pix] + ldh);
        outu[(size_t)k * P_ + tp0 + pix] = gm;
        if constexpr (!LAST) gmL[pix * K_ + k] = gm;
      }
    }
    if constexpr (!LAST) {
      __syncthreads();
      if (tid < TILE) {
        int p = tp0 + tid;
        float l[K_];
        float mx = -1e30f;
#pragma unroll
        for (int k2 = 0; k2 < K_; k2++) {
          l[k2] = predu[(size_t)k2 * P_ + p] + gmL[tid * K_ + k2];
          mx = fmaxf(mx, l[k2]);
        }
        float ssum = 0.f;
#pragma unroll
        for (int k2 = 0; k2 < K_; k2++) { l[k2] = expf(l[k2] - mx); ssum += l[k2]; }
        float inv = 1.f / ssum;
#pragma unroll
        for (int k2 = 0; k2 < K_; k2++) gpu[(size_t)k2 * P_ + p] = l[k2] * inv + EPSF;
      }
    }
  }
}

// ------------------------------------------------------------------ launch
extern "C" void kernel_launch(void* const* d_in, const int* in_sizes, int n_in,
                              void* d_out, int out_size, void* d_ws, size_t ws_size,
                              hipStream_t stream) {
  const float* img = (const float*)d_in[0];   // [B,3,128,128]
  const float* shf = (const float*)d_in[1];   // [B,8,3,128,128]
  const float* pred = (const float*)d_in[2];  // [B,6,128,128]
  float* out = (float*)d_out;                 // [B,6,128,128]
  float* wsf = (float*)d_ws;
  float* gp = wsf;                               // B*K*P
  float* p1 = gp + (size_t)B_ * K_ * P_;         // B*K*NCH*NF1
  float* p2 = p1 + (size_t)B_ * K_ * NCH * NF1;  // B*K*NCH*NF2

  k_softmax0<<<(B_ * P_) / 256, 256, 0, stream>>>(pred, gp);
  for (int step = 0; step < 3; step++) {
    k_reduce1<<<B_ * NCH * 2, 384, 0, stream>>>(img, shf, gp, p1);
    k_reduce2<<<B_ * NCH * 2, 384, 0, stream>>>(img, shf, gp, p1, p2);
    if (step < 2)
      k_estep<0><<<B_ * NCH, 768, 0, stream>>>(img, shf, pred, p1, p2, out, gp);
    else
      k_estep<1><<<B_ * NCH, 768, 0, stream>>>(img, shf, pred, p1, p2, out, gp);
  }
}

// Round 3
// 346.296 us; speedup vs baseline: 1.6625x; 1.6625x over previous
//
#include <hip/hip_runtime.h>
#include <math.h>

#define EPSF 1.1920928955078125e-07f  // np.float32 eps

constexpr int B_ = 16, S_ = 8, CH = 3, K_ = 6;
constexpr int P_ = 128 * 128;  // pixels per image
constexpr int NF1 = 106;       // per-k moments: 96 ops_first + 10 sym M2
constexpr int NF2 = 48;        // per-k sigma sums: 8 s * 6 sym
constexpr int NCR = 8;         // reduce chunks per image (2048 px each)
constexpr int NCE = 32;        // estep chunks per image (512 px each)

// bijective XCD swizzle (nwg % 8 == 0): same-u blocks land on one XCD
__device__ __forceinline__ int swz8(int bid, int nwg) {
  return (bid & 7) * (nwg >> 3) + (bid >> 3);
}
__device__ __forceinline__ float4 ld4(const float* p) { return *(const float4*)p; }
__device__ __forceinline__ void st4(float* p, float4 v) { *(float4*)p = v; }
__device__ __forceinline__ float dot4(float4 a, float4 b) {
  return a.x * b.x + a.y * b.y + a.z * b.z + a.w * b.w;
}
__device__ __forceinline__ float sum4(float4 a) { return a.x + a.y + a.z + a.w; }
__device__ __forceinline__ float4 mul4(float4 a, float4 b) {
  return make_float4(a.x * b.x, a.y * b.y, a.z * b.z, a.w * b.w);
}
// d = s - (o0*i0 + o1*i1 + o2*i2 + o3), componentwise over 4 pixels
__device__ __forceinline__ float4 dcomp(float4 s, float4 i0, float4 i1, float4 i2,
                                        const float* o) {
  float4 r;
  r.x = s.x - (o[0] * i0.x + o[1] * i1.x + o[2] * i2.x + o[3]);
  r.y = s.y - (o[0] * i0.y + o[1] * i1.y + o[2] * i2.y + o[3]);
  r.z = s.z - (o[0] * i0.z + o[1] * i1.z + o[2] * i2.z + o[3]);
  r.w = s.w - (o[0] * i0.w + o[1] * i1.w + o[2] * i2.w + o[3]);
  return r;
}
// 0.5-prescaled quadratic form (diag carries 0.5, offdiag carries 1.0)
__device__ __forceinline__ float quadf(float d0, float d1, float d2, const float* s) {
  return s[0] * d0 * d0 + s[1] * d0 * d1 + s[2] * d0 * d2 + s[3] * d1 * d1 +
         s[4] * d1 * d2 + s[5] * d2 * d2;
}

// ------------------------------------------------------------------ 4x4 inverse
__device__ __forceinline__ void inv4(const float* Ain, float* out) {
  float a[4][8];
#pragma unroll
  for (int i = 0; i < 4; i++) {
#pragma unroll
    for (int j = 0; j < 4; j++) { a[i][j] = Ain[i * 4 + j]; a[i][4 + j] = (i == j) ? 1.f : 0.f; }
  }
#pragma unroll
  for (int c = 0; c < 4; c++) {
    float piv = 1.f / a[c][c];
#pragma unroll
    for (int j = 0; j < 8; j++) a[c][j] *= piv;
#pragma unroll
    for (int r = 0; r < 4; r++) {
      if (r != c) {
        float f = a[r][c];
#pragma unroll
        for (int j = 0; j < 8; j++) a[r][j] -= f * a[c][j];
      }
    }
  }
#pragma unroll
  for (int i = 0; i < 4; i++)
#pragma unroll
    for (int j = 0; j < 4; j++) out[i * 4 + j] = a[i][4 + j];
}

// ------------------------------------------------------------------ softmax (step 0)
__global__ __launch_bounds__(256) void k_softmax0(const float* __restrict__ pred,
                                                  float* __restrict__ gp) {
  int g = blockIdx.x * 256 + threadIdx.x;
  int u = g >> 14, p = g & (P_ - 1);
  const float* pr = pred + ((size_t)u * K_) * P_ + p;
  float l[K_];
  float mx = -1e30f;
#pragma unroll
  for (int k = 0; k < K_; k++) { l[k] = pr[(size_t)k * P_]; mx = fmaxf(mx, l[k]); }
  float s = 0.f;
#pragma unroll
  for (int k = 0; k < K_; k++) { l[k] = expf(l[k] - mx); s += l[k]; }
  float inv = 1.f / s;
  float* gw = gp + ((size_t)u * K_) * P_ + p;
#pragma unroll
  for (int k = 0; k < K_; k++) gw[(size_t)k * P_] = l[k] * inv + EPSF;
}

// ------------------------------------------------------------------ reduce1
// grid = B*K*2*NCR blocks x 256 thr; one (u, k, s-half, chunk) each; no barriers in main loop.
__global__ __launch_bounds__(256) void k_reduce1(const float* __restrict__ img,
                                                 const float* __restrict__ shf,
                                                 const float* __restrict__ gp,
                                                 float* __restrict__ p1) {
  __shared__ float red[58][33];
  int wg = swz8(blockIdx.x, B_ * K_ * 2 * NCR);
  int u = wg / (K_ * 2 * NCR);
  int r = wg % (K_ * 2 * NCR);
  int k = r >> 4, shalf = (r >> 3) & 1, ch = r & 7;
  int tid = threadIdx.x, lane = tid & 63, w = tid >> 6;

  const float* imgu = img + (size_t)u * CH * P_;
  const float* shfu = shf + ((size_t)u * S_ + shalf * 4) * CH * P_;
  const float* gpu = gp + (size_t)(u * K_ + k) * P_;

  float acc[58];
#pragma unroll
  for (int i = 0; i < 58; i++) acc[i] = 0.f;

#pragma unroll
  for (int it = 0; it < 2; it++) {
    int p = ch * 2048 + it * 1024 + tid * 4;
    float4 i0 = ld4(imgu + p);
    float4 i1 = ld4(imgu + P_ + p);
    float4 i2 = ld4(imgu + 2 * P_ + p);
    float4 g = ld4(gpu + p);
    float4 t0 = mul4(g, i0), t1 = mul4(g, i1), t2 = mul4(g, i2);
#pragma unroll
    for (int sa = 0; sa < 12; sa++) {
      float4 s = ld4(shfu + sa * P_ + p);
      acc[sa * 4 + 0] += dot4(s, t0);
      acc[sa * 4 + 1] += dot4(s, t1);
      acc[sa * 4 + 2] += dot4(s, t2);
      acc[sa * 4 + 3] += dot4(s, g);
    }
    if (shalf == 0) {  // block-uniform branch: M2 only from half 0
      acc[48] += dot4(i0, t0); acc[49] += dot4(i1, t0); acc[50] += dot4(i2, t0);
      acc[51] += sum4(t0);
      acc[52] += dot4(i1, t1); acc[53] += dot4(i2, t1); acc[54] += sum4(t1);
      acc[55] += dot4(i2, t2); acc[56] += sum4(t2);
      acc[57] += sum4(g);
    }
  }
#pragma unroll
  for (int j = 0; j < 58; j++) {
    float v = acc[j];
    v += __shfl_xor(v, 1, 64);
    v += __shfl_xor(v, 2, 64);
    v += __shfl_xor(v, 4, 64);
    acc[j] = v;
  }
  if ((lane & 7) == 0) {
    int col = w * 8 + (lane >> 3);
#pragma unroll
    for (int j = 0; j < 58; j++) red[j][col] = acc[j];
  }
  __syncthreads();
  if (tid < 58) {
    float s = 0.f;
#pragma unroll
    for (int c = 0; c < 32; c++) s += red[tid][c];
    if (shalf == 0) {
      int off = (tid < 48) ? tid : 96 + (tid - 48);
      p1[((size_t)(u * K_ + k) * NCR + ch) * NF1 + off] = s;
    } else if (tid < 48) {
      p1[((size_t)(u * K_ + k) * NCR + ch) * NF1 + 48 + tid] = s;
    }
  }
}

// ------------------------------------------------------------------ reduce2
__global__ __launch_bounds__(256) void k_reduce2(const float* __restrict__ img,
                                                 const float* __restrict__ shf,
                                                 const float* __restrict__ gp,
                                                 const float* __restrict__ p1,
                                                 float* __restrict__ p2) {
  __shared__ float sum1[58];
  __shared__ float invA[16];
  __shared__ float opsS[48];
  __shared__ float nrmS[2];  // [0]=1/trace, [1]=1/sum(gp)
  __shared__ float red[24][33];
  int wg = swz8(blockIdx.x, B_ * K_ * 2 * NCR);
  int u = wg / (K_ * 2 * NCR);
  int r = wg % (K_ * 2 * NCR);
  int k = r >> 4, shalf = (r >> 3) & 1, ch = r & 7;
  int tid = threadIdx.x, lane = tid & 63, w = tid >> 6;

  if (tid < 58) {  // fixed-order chunk sums (only this block's half + M2)
    int idx = (tid < 48) ? (shalf * 48 + tid) : (96 + tid - 48);
    const float* src = p1 + (size_t)(u * K_ + k) * NCR * NF1 + idx;
    float s = 0.f;
#pragma unroll
    for (int c = 0; c < NCR; c++) s += src[c * NF1];
    sum1[tid] = s;
  }
  __syncthreads();
  if (tid == 0) {
    const float* m = &sum1[48];
    float tr = m[0] + m[4] + m[7] + m[9];
    float nrm = 1.f / tr;
    nrmS[0] = nrm;
    nrmS[1] = 1.f / m[9];
    const int sym[4][4] = {{0, 1, 2, 3}, {1, 4, 5, 6}, {2, 5, 7, 8}, {3, 6, 8, 9}};
    float A[16];
#pragma unroll
    for (int i = 0; i < 4; i++)
#pragma unroll
      for (int j = 0; j < 4; j++)
        A[i * 4 + j] = m[sym[i][j]] * nrm + ((i == j) ? EPSF : 0.f);
    inv4(A, invA);
  }
  __syncthreads();
  if (tid < 48) {
    int sa = tid >> 2, bc = tid & 3;
    float v = 0.f;
#pragma unroll
    for (int c = 0; c < 4; c++) v += sum1[sa * 4 + c] * invA[c * 4 + bc];
    opsS[tid] = v * nrmS[0];
  }
  __syncthreads();
  float opr[48];
#pragma unroll
  for (int j = 0; j < 48; j++) opr[j] = opsS[j];
  float pn = nrmS[1];

  const float* imgu = img + (size_t)u * CH * P_;
  const float* shfu = shf + ((size_t)u * S_ + shalf * 4) * CH * P_;
  const float* gpu = gp + (size_t)(u * K_ + k) * P_;

  float acc[24];
#pragma unroll
  for (int j = 0; j < 24; j++) acc[j] = 0.f;

#pragma unroll
  for (int it = 0; it < 2; it++) {
    int p = ch * 2048 + it * 1024 + tid * 4;
    float4 i0 = ld4(imgu + p);
    float4 i1 = ld4(imgu + P_ + p);
    float4 i2 = ld4(imgu + 2 * P_ + p);
    float4 g = ld4(gpu + p);
    float4 pp = make_float4(g.x * pn, g.y * pn, g.z * pn, g.w * pn);
#pragma unroll
    for (int sl = 0; sl < 4; sl++) {
      const float* o = &opr[sl * 12];
      float4 d0 = dcomp(ld4(shfu + (sl * 3 + 0) * P_ + p), i0, i1, i2, o);
      float4 d1 = dcomp(ld4(shfu + (sl * 3 + 1) * P_ + p), i0, i1, i2, o + 4);
      float4 d2 = dcomp(ld4(shfu + (sl * 3 + 2) * P_ + p), i0, i1, i2, o + 8);
      float4 q0 = mul4(pp, d0), q1 = mul4(pp, d1), q2 = mul4(pp, d2);
      acc[sl * 6 + 0] += dot4(q0, d0);
      acc[sl * 6 + 1] += dot4(q0, d1);
      acc[sl * 6 + 2] += dot4(q0, d2);
      acc[sl * 6 + 3] += dot4(q1, d1);
      acc[sl * 6 + 4] += dot4(q1, d2);
      acc[sl * 6 + 5] += dot4(q2, d2);
    }
  }
#pragma unroll
  for (int j = 0; j < 24; j++) {
    float v = acc[j];
    v += __shfl_xor(v, 1, 64);
    v += __shfl_xor(v, 2, 64);
    v += __shfl_xor(v, 4, 64);
    acc[j] = v;
  }
  if ((lane & 7) == 0) {
    int col = w * 8 + (lane >> 3);
#pragma unroll
    for (int j = 0; j < 24; j++) red[j][col] = acc[j];
  }
  __syncthreads();
  if (tid < 24) {
    float s = 0.f;
#pragma unroll
    for (int c = 0; c < 32; c++) s += red[tid][c];
    p2[((size_t)(u * K_ + k) * NCR + ch) * NF2 + shalf * 24 + tid] = s;
  }
}

// ------------------------------------------------------------------ e-step (+ fused softmax)
// grid = B*NCE blocks x 768 thr = 12 waves = (6 k) x (2 s-halves); one 512-px chunk; 2 barriers.
template <int LAST>
__global__ __launch_bounds__(768) void k_estep(const float* __restrict__ img,
                                               const float* __restrict__ shf,
                                               const float* __restrict__ pred,
                                               const float* __restrict__ p1,
                                               const float* __restrict__ p2,
                                               float* __restrict__ out,
                                               float* __restrict__ gp) {
  __shared__ float sum1[K_][NF1];
  __shared__ float sum2[K_][NF2];
  __shared__ float invA[K_][16];
  __shared__ float normL[K_];
  __shared__ float opsL[K_][96];
  __shared__ float sinvL[K_ * S_ * 6];
  __shared__ float ldetL[K_ * S_];
  __shared__ float ldhL[K_];
  __shared__ float qL[K_][512];
  __shared__ float gmL[K_][512];

  int wg = swz8(blockIdx.x, B_ * NCE);
  int u = wg >> 5, ch = wg & 31;
  int tid = threadIdx.x, lane = tid & 63, w = tid >> 6;
  int k = w >> 1, shalf = w & 1;

  for (int e = tid; e < K_ * NF1; e += 768) {
    int kk = e / NF1, i = e % NF1;
    const float* src = p1 + (size_t)(u * K_ + kk) * NCR * NF1 + i;
    float s = 0.f;
#pragma unroll
    for (int c = 0; c < NCR; c++) s += src[c * NF1];
    sum1[kk][i] = s;
  }
  for (int e = tid; e < K_ * NF2; e += 768) {
    int kk = e / NF2, j = e % NF2;
    const float* src = p2 + (size_t)(u * K_ + kk) * NCR * NF2 + j;
    float s = 0.f;
#pragma unroll
    for (int c = 0; c < NCR; c++) s += src[c * NF2];
    sum2[kk][j] = s;
  }
  __syncthreads();
  if (tid < K_) {
    const float* m = &sum1[tid][96];
    float tr = m[0] + m[4] + m[7] + m[9];
    float nrm = 1.f / tr;
    normL[tid] = nrm;
    const int sym[4][4] = {{0, 1, 2, 3}, {1, 4, 5, 6}, {2, 5, 7, 8}, {3, 6, 8, 9}};
    float A[16];
#pragma unroll
    for (int i = 0; i < 4; i++)
#pragma unroll
      for (int j = 0; j < 4; j++)
        A[i * 4 + j] = m[sym[i][j]] * nrm + ((i == j) ? EPSF : 0.f);
    inv4(A, invA[tid]);
  } else if (tid >= 64 && tid < 64 + K_ * S_) {
    int t2 = tid - 64;  // k*8+s
    const float* m = &sum2[t2 >> 3][(t2 & 7) * 6];
    float a = m[0] + EPSF, b = m[1], c = m[2];
    float d = m[3] + EPSF, e2 = m[4], f = m[5] + EPSF;
    float c00 = d * f - e2 * e2, c01 = c * e2 - b * f, c02 = b * e2 - c * d;
    float det = a * c00 + b * c01 + c * c02;
    float id = 1.f / det;
    sinvL[t2 * 6 + 0] = 0.5f * c00 * id;
    sinvL[t2 * 6 + 1] = c01 * id;
    sinvL[t2 * 6 + 2] = c02 * id;
    sinvL[t2 * 6 + 3] = 0.5f * (a * f - c * c) * id;
    sinvL[t2 * 6 + 4] = (c * b - a * e2) * id;
    sinvL[t2 * 6 + 5] = 0.5f * (a * d - b * b) * id;
    ldetL[t2] = logf(det);
  }
  __syncthreads();
  for (int e = tid; e < K_ * 96; e += 768) {
    int kk = e / 96, r = e % 96, sa = r >> 2, bc = r & 3;
    float v = 0.f;
#pragma unroll
    for (int c = 0; c < 4; c++) v += sum1[kk][sa * 4 + c] * invA[kk][c * 4 + bc];
    opsL[kk][r] = v * normL[kk];
  }
  if (tid < K_) {
    float s = 0.f;
#pragma unroll
    for (int si = 0; si < S_; si++) s += ldetL[tid * S_ + si];
    ldhL[tid] = 0.5f * s;
  }
  __syncthreads();

  float opr[48], svv[24];
#pragma unroll
  for (int j = 0; j < 48; j++) opr[j] = opsL[k][shalf * 48 + j];
#pragma unroll
  for (int j = 0; j < 24; j++) svv[j] = sinvL[(k * S_ + shalf * 4) * 6 + j];
  float ldh = ldhL[k];

  const float* imgu = img + (size_t)u * CH * P_;
  const float* shfu = shf + ((size_t)u * S_ + shalf * 4) * CH * P_;

  float4 qq[2];
#pragma unroll
  for (int iq = 0; iq < 2; iq++) {
    int px = (iq * 64 + lane) * 4;
    int p = ch * 512 + px;
    float4 i0 = ld4(imgu + p);
    float4 i1 = ld4(imgu + P_ + p);
    float4 i2 = ld4(imgu + 2 * P_ + p);
    float4 q = make_float4(0.f, 0.f, 0.f, 0.f);
#pragma unroll
    for (int sl = 0; sl < 4; sl++) {
      const float* o = &opr[sl * 12];
      float4 d0 = dcomp(ld4(shfu + (sl * 3 + 0) * P_ + p), i0, i1, i2, o);
      float4 d1 = dcomp(ld4(shfu + (sl * 3 + 1) * P_ + p), i0, i1, i2, o + 4);
      float4 d2 = dcomp(ld4(shfu + (sl * 3 + 2) * P_ + p), i0, i1, i2, o + 8);
      const float* sp = &svv[sl * 6];
      q.x += quadf(d0.x, d1.x, d2.x, sp);
      q.y += quadf(d0.y, d1.y, d2.y, sp);
      q.z += quadf(d0.z, d1.z, d2.z, sp);
      q.w += quadf(d0.w, d1.w, d2.w, sp);
    }
    qq[iq] = q;
    if (shalf == 1) st4(&qL[k][px], q);
  }
  __syncthreads();
  if (shalf == 0) {
    float* outu = out + (size_t)(u * K_ + k) * P_;
#pragma unroll
    for (int iq = 0; iq < 2; iq++) {
      int px = (iq * 64 + lane) * 4;
      float4 qh = *(const float4*)&qL[k][px];
      float4 g4;
      g4.x = -(qq[iq].x + qh.x + ldh);
      g4.y = -(qq[iq].y + qh.y + ldh);
      g4.z = -(qq[iq].z + qh.z + ldh);
      g4.w = -(qq[iq].w + qh.w + ldh);
      st4(outu + ch * 512 + px, g4);
      if constexpr (!LAST) st4(&gmL[k][px], g4);
    }
  }
  if constexpr (!LAST) {
    __syncthreads();
    if (tid < 512) {
      int p = ch * 512 + tid;
      const float* predu = pred + (size_t)u * K_ * P_;
      float* gpu = gp + (size_t)u * K_ * P_;
      float l[K_];
      float mx = -1e30f;
#pragma unroll
      for (int k2 = 0; k2 < K_; k2++) {
        l[k2] = predu[(size_t)k2 * P_ + p] + gmL[k2][tid];
        mx = fmaxf(mx, l[k2]);
      }
      float ss = 0.f;
#pragma unroll
      for (int k2 = 0; k2 < K_; k2++) { l[k2] = expf(l[k2] - mx); ss += l[k2]; }
      float inv = 1.f / ss;
#pragma unroll
      for (int k2 = 0; k2 < K_; k2++) gpu[(size_t)k2 * P_ + p] = l[k2] * inv + EPSF;
    }
  }
}

// ------------------------------------------------------------------ launch
extern "C" void kernel_launch(void* const* d_in, const int* in_sizes, int n_in,
                              void* d_out, int out_size, void* d_ws, size_t ws_size,
                              hipStream_t stream) {
  const float* img = (const float*)d_in[0];   // [B,3,128,128]
  const float* shf = (const float*)d_in[1];   // [B,8,3,128,128]
  const float* pred = (const float*)d_in[2];  // [B,6,128,128]
  float* out = (float*)d_out;                 // [B,6,128,128]
  float* wsf = (float*)d_ws;
  float* gp = wsf;                               // B*K*P
  float* p1 = gp + (size_t)B_ * K_ * P_;         // B*K*NCR*NF1
  float* p2 = p1 + (size_t)B_ * K_ * NCR * NF1;  // B*K*NCR*NF2

  k_softmax0<<<(B_ * P_) / 256, 256, 0, stream>>>(pred, gp);
  for (int step = 0; step < 3; step++) {
    k_reduce1<<<B_ * K_ * 2 * NCR, 256, 0, stream>>>(img, shf, gp, p1);
    k_reduce2<<<B_ * K_ * 2 * NCR, 256, 0, stream>>>(img, shf, gp, p1, p2);
    if (step < 2)
      k_estep<0><<<B_ * NCE, 768, 0, stream>>>(img, shf, pred, p1, p2, out, gp);
    else
      k_estep<1><<<B_ * NCE, 768, 0, stream>>>(img, shf, pred, p1, p2, out, gp);
  }
}

// Round 4
// 242.880 us; speedup vs baseline: 2.3704x; 1.4258x over previous
//
#include <hip/hip_runtime.h>
#include <math.h>

#define EPSF 1.1920928955078125e-07f  // np.float32 eps

constexpr int B_ = 16, S_ = 8, CH = 3, K_ = 6;
constexpr int P_ = 128 * 128;  // pixels per image
constexpr int NF1 = 106;       // per-k moments: 96 ops_first + 10 sym M2
constexpr int NF2 = 48;        // per-k sigma sums: 8 s * 6 sym
constexpr int NCR = 8;         // reduce chunks per image (2048 px each)
constexpr int NCE = 32;        // estep chunks per image (512 px each)

// bijective XCD swizzle (nwg % 8 == 0): same-u blocks land on one XCD
__device__ __forceinline__ int swz8(int bid, int nwg) {
  return (bid & 7) * (nwg >> 3) + (bid >> 3);
}
__device__ __forceinline__ float4 ld4(const float* p) { return *(const float4*)p; }
__device__ __forceinline__ void st4(float* p, float4 v) { *(float4*)p = v; }
__device__ __forceinline__ float dot4(float4 a, float4 b) {
  return a.x * b.x + a.y * b.y + a.z * b.z + a.w * b.w;
}
__device__ __forceinline__ float sum4(float4 a) { return a.x + a.y + a.z + a.w; }
__device__ __forceinline__ float4 mul4(float4 a, float4 b) {
  return make_float4(a.x * b.x, a.y * b.y, a.z * b.z, a.w * b.w);
}
// d = s - (o.x*i0 + o.y*i1 + o.z*i2 + o.w), componentwise over 4 pixels
__device__ __forceinline__ float4 dcompv(float4 s, float4 i0, float4 i1, float4 i2,
                                         float4 o) {
  float4 r;
  r.x = s.x - (o.x * i0.x + o.y * i1.x + o.z * i2.x + o.w);
  r.y = s.y - (o.x * i0.y + o.y * i1.y + o.z * i2.y + o.w);
  r.z = s.z - (o.x * i0.z + o.y * i1.z + o.z * i2.z + o.w);
  r.w = s.w - (o.x * i0.w + o.y * i1.w + o.z * i2.w + o.w);
  return r;
}
// 0.5-prescaled quadratic form (diag carries 0.5, offdiag carries 1.0)
__device__ __forceinline__ float quadv(float d0, float d1, float d2, float4 sA,
                                       float2 sB) {
  return sA.x * d0 * d0 + sA.y * d0 * d1 + sA.z * d0 * d2 + sA.w * d1 * d1 +
         sB.x * d1 * d2 + sB.y * d2 * d2;
}

// ------------------------------------------------------------------ 4x4 inverse
__device__ __forceinline__ void inv4(const float* Ain, float* out) {
  float a[4][8];
#pragma unroll
  for (int i = 0; i < 4; i++) {
#pragma unroll
    for (int j = 0; j < 4; j++) { a[i][j] = Ain[i * 4 + j]; a[i][4 + j] = (i == j) ? 1.f : 0.f; }
  }
#pragma unroll
  for (int c = 0; c < 4; c++) {
    float piv = 1.f / a[c][c];
#pragma unroll
    for (int j = 0; j < 8; j++) a[c][j] *= piv;
#pragma unroll
    for (int r = 0; r < 4; r++) {
      if (r != c) {
        float f = a[r][c];
#pragma unroll
        for (int j = 0; j < 8; j++) a[r][j] -= f * a[c][j];
      }
    }
  }
#pragma unroll
  for (int i = 0; i < 4; i++)
#pragma unroll
    for (int j = 0; j < 4; j++) out[i * 4 + j] = a[i][4 + j];
}

// ------------------------------------------------------------------ softmax (step 0)
__global__ __launch_bounds__(256) void k_softmax0(const float* __restrict__ pred,
                                                  float* __restrict__ gp) {
  int g = blockIdx.x * 256 + threadIdx.x;
  int u = g >> 14, p = g & (P_ - 1);
  const float* pr = pred + ((size_t)u * K_) * P_ + p;
  float l[K_];
  float mx = -1e30f;
#pragma unroll
  for (int k = 0; k < K_; k++) { l[k] = pr[(size_t)k * P_]; mx = fmaxf(mx, l[k]); }
  float s = 0.f;
#pragma unroll
  for (int k = 0; k < K_; k++) { l[k] = expf(l[k] - mx); s += l[k]; }
  float inv = 1.f / s;
  float* gw = gp + ((size_t)u * K_) * P_ + p;
#pragma unroll
  for (int k = 0; k < K_; k++) gw[(size_t)k * P_] = l[k] * inv + EPSF;
}

// ------------------------------------------------------------------ reduce1
// grid = B*K*2*NCR blocks x 256 thr; one (u, k, s-half, chunk) each; no barriers in main loop.
__global__ __launch_bounds__(256, 4) void k_reduce1(const float* __restrict__ img,
                                                    const float* __restrict__ shf,
                                                    const float* __restrict__ gp,
                                                    float* __restrict__ p1) {
  __shared__ float red[58][33];
  int wg = swz8(blockIdx.x, B_ * K_ * 2 * NCR);
  int u = wg / (K_ * 2 * NCR);
  int r = wg % (K_ * 2 * NCR);
  int k = r >> 4, shalf = (r >> 3) & 1, ch = r & 7;
  int tid = threadIdx.x, lane = tid & 63, w = tid >> 6;

  const float* imgu = img + (size_t)u * CH * P_;
  const float* shfu = shf + ((size_t)u * S_ + shalf * 4) * CH * P_;
  const float* gpu = gp + (size_t)(u * K_ + k) * P_;

  float acc[58];
#pragma unroll
  for (int i = 0; i < 58; i++) acc[i] = 0.f;

#pragma unroll
  for (int it = 0; it < 2; it++) {
    int p = ch * 2048 + it * 1024 + tid * 4;
    float4 i0 = ld4(imgu + p);
    float4 i1 = ld4(imgu + P_ + p);
    float4 i2 = ld4(imgu + 2 * P_ + p);
    float4 g = ld4(gpu + p);
    float4 t0 = mul4(g, i0), t1 = mul4(g, i1), t2 = mul4(g, i2);
#pragma unroll
    for (int sa = 0; sa < 12; sa++) {
      float4 s = ld4(shfu + sa * P_ + p);
      acc[sa * 4 + 0] += dot4(s, t0);
      acc[sa * 4 + 1] += dot4(s, t1);
      acc[sa * 4 + 2] += dot4(s, t2);
      acc[sa * 4 + 3] += dot4(s, g);
    }
    if (shalf == 0) {  // block-uniform branch: M2 only from half 0
      acc[48] += dot4(i0, t0); acc[49] += dot4(i1, t0); acc[50] += dot4(i2, t0);
      acc[51] += sum4(t0);
      acc[52] += dot4(i1, t1); acc[53] += dot4(i2, t1); acc[54] += sum4(t1);
      acc[55] += dot4(i2, t2); acc[56] += sum4(t2);
      acc[57] += sum4(g);
    }
  }
#pragma unroll
  for (int j = 0; j < 58; j++) {
    float v = acc[j];
    v += __shfl_xor(v, 1, 64);
    v += __shfl_xor(v, 2, 64);
    v += __shfl_xor(v, 4, 64);
    acc[j] = v;
  }
  if ((lane & 7) == 0) {
    int col = w * 8 + (lane >> 3);
#pragma unroll
    for (int j = 0; j < 58; j++) red[j][col] = acc[j];
  }
  __syncthreads();
  if (tid < 58) {
    float s = 0.f;
#pragma unroll
    for (int c = 0; c < 32; c++) s += red[tid][c];
    if (shalf == 0) {
      int off = (tid < 48) ? tid : 96 + (tid - 48);
      p1[((size_t)(u * K_ + k) * NCR + ch) * NF1 + off] = s;
    } else if (tid < 48) {
      p1[((size_t)(u * K_ + k) * NCR + ch) * NF1 + 48 + tid] = s;
    }
  }
}

// ------------------------------------------------------------------ reduce2
__global__ __launch_bounds__(256, 4) void k_reduce2(const float* __restrict__ img,
                                                    const float* __restrict__ shf,
                                                    const float* __restrict__ gp,
                                                    const float* __restrict__ p1,
                                                    float* __restrict__ p2) {
  __shared__ float sum1[58];
  __shared__ float invA[16];
  __shared__ __align__(16) float opsS[48];
  __shared__ float nrmS[2];  // [0]=1/trace, [1]=1/sum(gp)
  __shared__ float red[24][33];
  int wg = swz8(blockIdx.x, B_ * K_ * 2 * NCR);
  int u = wg / (K_ * 2 * NCR);
  int r = wg % (K_ * 2 * NCR);
  int k = r >> 4, shalf = (r >> 3) & 1, ch = r & 7;
  int tid = threadIdx.x, lane = tid & 63, w = tid >> 6;

  if (tid < 58) {  // fixed-order chunk sums (only this block's half + M2)
    int idx = (tid < 48) ? (shalf * 48 + tid) : (96 + tid - 48);
    const float* src = p1 + (size_t)(u * K_ + k) * NCR * NF1 + idx;
    float s = 0.f;
#pragma unroll
    for (int c = 0; c < NCR; c++) s += src[c * NF1];
    sum1[tid] = s;
  }
  __syncthreads();
  if (tid == 0) {
    const float* m = &sum1[48];
    float tr = m[0] + m[4] + m[7] + m[9];
    float nrm = 1.f / tr;
    nrmS[0] = nrm;
    nrmS[1] = 1.f / m[9];
    const int sym[4][4] = {{0, 1, 2, 3}, {1, 4, 5, 6}, {2, 5, 7, 8}, {3, 6, 8, 9}};
    float A[16];
#pragma unroll
    for (int i = 0; i < 4; i++)
#pragma unroll
      for (int j = 0; j < 4; j++)
        A[i * 4 + j] = m[sym[i][j]] * nrm + ((i == j) ? EPSF : 0.f);
    inv4(A, invA);
  }
  __syncthreads();
  if (tid < 48) {
    int sa = tid >> 2, bc = tid & 3;
    float v = 0.f;
#pragma unroll
    for (int c = 0; c < 4; c++) v += sum1[sa * 4 + c] * invA[c * 4 + bc];
    opsS[tid] = v * nrmS[0];
  }
  __syncthreads();
  float pn = nrmS[1];

  const float* imgu = img + (size_t)u * CH * P_;
  const float* shfu = shf + ((size_t)u * S_ + shalf * 4) * CH * P_;
  const float* gpu = gp + (size_t)(u * K_ + k) * P_;

  float acc[24];
#pragma unroll
  for (int j = 0; j < 24; j++) acc[j] = 0.f;

#pragma unroll
  for (int it = 0; it < 2; it++) {
    int p = ch * 2048 + it * 1024 + tid * 4;
    float4 i0 = ld4(imgu + p);
    float4 i1 = ld4(imgu + P_ + p);
    float4 i2 = ld4(imgu + 2 * P_ + p);
    float4 g = ld4(gpu + p);
    float4 pp = make_float4(g.x * pn, g.y * pn, g.z * pn, g.w * pn);
#pragma unroll
    for (int sl = 0; sl < 4; sl++) {
      // wave-uniform LDS broadcasts (keeps register pressure low, no spills)
      float4 oA = ld4(&opsS[sl * 12 + 0]);
      float4 oB = ld4(&opsS[sl * 12 + 4]);
      float4 oC = ld4(&opsS[sl * 12 + 8]);
      float4 d0 = dcompv(ld4(shfu + (sl * 3 + 0) * P_ + p), i0, i1, i2, oA);
      float4 d1 = dcompv(ld4(shfu + (sl * 3 + 1) * P_ + p), i0, i1, i2, oB);
      float4 d2 = dcompv(ld4(shfu + (sl * 3 + 2) * P_ + p), i0, i1, i2, oC);
      float4 q0 = mul4(pp, d0), q1 = mul4(pp, d1), q2 = mul4(pp, d2);
      acc[sl * 6 + 0] += dot4(q0, d0);
      acc[sl * 6 + 1] += dot4(q0, d1);
      acc[sl * 6 + 2] += dot4(q0, d2);
      acc[sl * 6 + 3] += dot4(q1, d1);
      acc[sl * 6 + 4] += dot4(q1, d2);
      acc[sl * 6 + 5] += dot4(q2, d2);
    }
  }
#pragma unroll
  for (int j = 0; j < 24; j++) {
    float v = acc[j];
    v += __shfl_xor(v, 1, 64);
    v += __shfl_xor(v, 2, 64);
    v += __shfl_xor(v, 4, 64);
    acc[j] = v;
  }
  if ((lane & 7) == 0) {
    int col = w * 8 + (lane >> 3);
#pragma unroll
    for (int j = 0; j < 24; j++) red[j][col] = acc[j];
  }
  __syncthreads();
  if (tid < 24) {
    float s = 0.f;
#pragma unroll
    for (int c = 0; c < 32; c++) s += red[tid][c];
    p2[((size_t)(u * K_ + k) * NCR + ch) * NF2 + shalf * 24 + tid] = s;
  }
}

// ------------------------------------------------------------------ e-step (+ fused softmax)
// grid = B*NCE blocks x 768 thr = 12 waves = (6 k) x (2 s-halves); one 512-px chunk; 2 barriers.
template <int LAST>
__global__ __launch_bounds__(768, 3) void k_estep(const float* __restrict__ img,
                                                  const float* __restrict__ shf,
                                                  const float* __restrict__ pred,
                                                  const float* __restrict__ p1,
                                                  const float* __restrict__ p2,
                                                  float* __restrict__ out,
                                                  float* __restrict__ gp) {
  __shared__ float sum1[K_][NF1];
  __shared__ float sum2[K_][NF2];
  __shared__ float invA[K_][16];
  __shared__ float normL[K_];
  __shared__ __align__(16) float opsL[K_][96];
  __shared__ __align__(16) float sinvL[K_ * S_ * 8];  // padded stride 8
  __shared__ float ldetL[K_ * S_];
  __shared__ float ldhL[K_];
  __shared__ __align__(16) float qL[K_][512];
  __shared__ __align__(16) float gmL[K_][512];

  int wg = swz8(blockIdx.x, B_ * NCE);
  int u = wg >> 5, ch = wg & 31;
  int tid = threadIdx.x, lane = tid & 63, w = tid >> 6;
  int k = w >> 1, shalf = w & 1;

  for (int e = tid; e < K_ * NF1; e += 768) {
    int kk = e / NF1, i = e % NF1;
    const float* src = p1 + (size_t)(u * K_ + kk) * NCR * NF1 + i;
    float s = 0.f;
#pragma unroll
    for (int c = 0; c < NCR; c++) s += src[c * NF1];
    sum1[kk][i] = s;
  }
  for (int e = tid; e < K_ * NF2; e += 768) {
    int kk = e / NF2, j = e % NF2;
    const float* src = p2 + (size_t)(u * K_ + kk) * NCR * NF2 + j;
    float s = 0.f;
#pragma unroll
    for (int c = 0; c < NCR; c++) s += src[c * NF2];
    sum2[kk][j] = s;
  }
  __syncthreads();
  if (tid < K_) {
    const float* m = &sum1[tid][96];
    float tr = m[0] + m[4] + m[7] + m[9];
    float nrm = 1.f / tr;
    normL[tid] = nrm;
    const int sym[4][4] = {{0, 1, 2, 3}, {1, 4, 5, 6}, {2, 5, 7, 8}, {3, 6, 8, 9}};
    float A[16];
#pragma unroll
    for (int i = 0; i < 4; i++)
#pragma unroll
      for (int j = 0; j < 4; j++)
        A[i * 4 + j] = m[sym[i][j]] * nrm + ((i == j) ? EPSF : 0.f);
    inv4(A, invA[tid]);
  } else if (tid >= 64 && tid < 64 + K_ * S_) {
    int t2 = tid - 64;  // k*8+s
    const float* m = &sum2[t2 >> 3][(t2 & 7) * 6];
    float a = m[0] + EPSF, b = m[1], c = m[2];
    float d = m[3] + EPSF, e2 = m[4], f = m[5] + EPSF;
    float c00 = d * f - e2 * e2, c01 = c * e2 - b * f, c02 = b * e2 - c * d;
    float det = a * c00 + b * c01 + c * c02;
    float id = 1.f / det;
    sinvL[t2 * 8 + 0] = 0.5f * c00 * id;
    sinvL[t2 * 8 + 1] = c01 * id;
    sinvL[t2 * 8 + 2] = c02 * id;
    sinvL[t2 * 8 + 3] = 0.5f * (a * f - c * c) * id;
    sinvL[t2 * 8 + 4] = (c * b - a * e2) * id;
    sinvL[t2 * 8 + 5] = 0.5f * (a * d - b * b) * id;
    sinvL[t2 * 8 + 6] = 0.f;
    sinvL[t2 * 8 + 7] = 0.f;
    ldetL[t2] = logf(det);
  }
  __syncthreads();
  for (int e = tid; e < K_ * 96; e += 768) {
    int kk = e / 96, r = e % 96, sa = r >> 2, bc = r & 3;
    float v = 0.f;
#pragma unroll
    for (int c = 0; c < 4; c++) v += sum1[kk][sa * 4 + c] * invA[kk][c * 4 + bc];
    opsL[kk][r] = v * normL[kk];
  }
  if (tid < K_) {
    float s = 0.f;
#pragma unroll
    for (int si = 0; si < S_; si++) s += ldetL[tid * S_ + si];
    ldhL[tid] = 0.5f * s;
  }
  __syncthreads();

  const float* ob = &opsL[k][shalf * 48];
  const float* sb = &sinvL[(k * S_ + shalf * 4) * 8];
  float ldh = ldhL[k];

  const float* imgu = img + (size_t)u * CH * P_;
  const float* shfu = shf + ((size_t)u * S_ + shalf * 4) * CH * P_;

  int p0 = ch * 512 + lane * 4;  // iq=0; iq=1 is +256
  float4 i0a = ld4(imgu + p0),          i0b = ld4(imgu + p0 + 256);
  float4 i1a = ld4(imgu + P_ + p0),     i1b = ld4(imgu + P_ + p0 + 256);
  float4 i2a = ld4(imgu + 2 * P_ + p0), i2b = ld4(imgu + 2 * P_ + p0 + 256);
  float4 qa = make_float4(0.f, 0.f, 0.f, 0.f);
  float4 qb = make_float4(0.f, 0.f, 0.f, 0.f);
#pragma unroll
  for (int sl = 0; sl < 4; sl++) {
    float4 oA = ld4(ob + sl * 12 + 0);
    float4 oB = ld4(ob + sl * 12 + 4);
    float4 oC = ld4(ob + sl * 12 + 8);
    float4 sA = ld4(sb + sl * 8);
    float2 sB = *(const float2*)(sb + sl * 8 + 4);
    const float* s0 = shfu + (sl * 3 + 0) * P_;
    const float* s1 = shfu + (sl * 3 + 1) * P_;
    const float* s2 = shfu + (sl * 3 + 2) * P_;
    {
      float4 d0 = dcompv(ld4(s0 + p0), i0a, i1a, i2a, oA);
      float4 d1 = dcompv(ld4(s1 + p0), i0a, i1a, i2a, oB);
      float4 d2 = dcompv(ld4(s2 + p0), i0a, i1a, i2a, oC);
      qa.x += quadv(d0.x, d1.x, d2.x, sA, sB);
      qa.y += quadv(d0.y, d1.y, d2.y, sA, sB);
      qa.z += quadv(d0.z, d1.z, d2.z, sA, sB);
      qa.w += quadv(d0.w, d1.w, d2.w, sA, sB);
    }
    {
      float4 d0 = dcompv(ld4(s0 + p0 + 256), i0b, i1b, i2b, oA);
      float4 d1 = dcompv(ld4(s1 + p0 + 256), i0b, i1b, i2b, oB);
      float4 d2 = dcompv(ld4(s2 + p0 + 256), i0b, i1b, i2b, oC);
      qb.x += quadv(d0.x, d1.x, d2.x, sA, sB);
      qb.y += quadv(d0.y, d1.y, d2.y, sA, sB);
      qb.z += quadv(d0.z, d1.z, d2.z, sA, sB);
      qb.w += quadv(d0.w, d1.w, d2.w, sA, sB);
    }
  }
  int pxa = lane * 4, pxb = lane * 4 + 256;
  if (shalf == 1) {
    st4(&qL[k][pxa], qa);
    st4(&qL[k][pxb], qb);
  }
  __syncthreads();
  if (shalf == 0) {
    float* outu = out + (size_t)(u * K_ + k) * P_;
    float4 qha = ld4(&qL[k][pxa]);
    float4 qhb = ld4(&qL[k][pxb]);
    float4 g4a, g4b;
    g4a.x = -(qa.x + qha.x + ldh); g4a.y = -(qa.y + qha.y + ldh);
    g4a.z = -(qa.z + qha.z + ldh); g4a.w = -(qa.w + qha.w + ldh);
    g4b.x = -(qb.x + qhb.x + ldh); g4b.y = -(qb.y + qhb.y + ldh);
    g4b.z = -(qb.z + qhb.z + ldh); g4b.w = -(qb.w + qhb.w + ldh);
    st4(outu + ch * 512 + pxa, g4a);
    st4(outu + ch * 512 + pxb, g4b);
    if constexpr (!LAST) {
      st4(&gmL[k][pxa], g4a);
      st4(&gmL[k][pxb], g4b);
    }
  }
  if constexpr (!LAST) {
    __syncthreads();
    if (tid < 512) {
      int p = ch * 512 + tid;
      const float* predu = pred + (size_t)u * K_ * P_;
      float* gpu = gp + (size_t)u * K_ * P_;
      float l[K_];
      float mx = -1e30f;
#pragma unroll
      for (int k2 = 0; k2 < K_; k2++) {
        l[k2] = predu[(size_t)k2 * P_ + p] + gmL[k2][tid];
        mx = fmaxf(mx, l[k2]);
      }
      float ss = 0.f;
#pragma unroll
      for (int k2 = 0; k2 < K_; k2++) { l[k2] = expf(l[k2] - mx); ss += l[k2]; }
      float inv = 1.f / ss;
#pragma unroll
      for (int k2 = 0; k2 < K_; k2++) gpu[(size_t)k2 * P_ + p] = l[k2] * inv + EPSF;
    }
  }
}

// ------------------------------------------------------------------ launch
extern "C" void kernel_launch(void* const* d_in, const int* in_sizes, int n_in,
                              void* d_out, int out_size, void* d_ws, size_t ws_size,
                              hipStream_t stream) {
  const float* img = (const float*)d_in[0];   // [B,3,128,128]
  const float* shf = (const float*)d_in[1];   // [B,8,3,128,128]
  const float* pred = (const float*)d_in[2];  // [B,6,128,128]
  float* out = (float*)d_out;                 // [B,6,128,128]
  float* wsf = (float*)d_ws;
  float* gp = wsf;                               // B*K*P
  float* p1 = gp + (size_t)B_ * K_ * P_;         // B*K*NCR*NF1
  float* p2 = p1 + (size_t)B_ * K_ * NCR * NF1;  // B*K*NCR*NF2

  k_softmax0<<<(B_ * P_) / 256, 256, 0, stream>>>(pred, gp);
  for (int step = 0; step < 3; step++) {
    k_reduce1<<<B_ * K_ * 2 * NCR, 256, 0, stream>>>(img, shf, gp, p1);
    k_reduce2<<<B_ * K_ * 2 * NCR, 256, 0, stream>>>(img, shf, gp, p1, p2);
    if (step < 2)
      k_estep<0><<<B_ * NCE, 768, 0, stream>>>(img, shf, pred, p1, p2, out, gp);
    else
      k_estep<1><<<B_ * NCE, 768, 0, stream>>>(img, shf, pred, p1, p2, out, gp);
  }
}

// Round 5
// 203.552 us; speedup vs baseline: 2.8284x; 1.1932x over previous
//
#include <hip/hip_runtime.h>
#include <math.h>

#define EPSF 1.1920928955078125e-07f  // np.float32 eps

constexpr int B_ = 16, S_ = 8, CH = 3, K_ = 6;
constexpr int P_ = 128 * 128;  // pixels per image
constexpr int NF1 = 106;       // per-k moments: 96 ops_first + 10 sym M2
constexpr int NF2 = 48;        // per-k sigma sums: 8 s * 6 sym
constexpr int NCR = 4;         // reduce chunks per image (4096 px each)
constexpr int NCE = 32;        // estep chunks per image (512 px each)

// bijective XCD swizzle (nwg % 8 == 0): same-u blocks land on one XCD
__device__ __forceinline__ int swz8(int bid, int nwg) {
  return (bid & 7) * (nwg >> 3) + (bid >> 3);
}
__device__ __forceinline__ float4 ld4(const float* p) { return *(const float4*)p; }
__device__ __forceinline__ void st4(float* p, float4 v) { *(float4*)p = v; }
__device__ __forceinline__ float dot4(float4 a, float4 b) {
  return a.x * b.x + a.y * b.y + a.z * b.z + a.w * b.w;
}
__device__ __forceinline__ float sum4(float4 a) { return a.x + a.y + a.z + a.w; }
__device__ __forceinline__ float4 mul4(float4 a, float4 b) {
  return make_float4(a.x * b.x, a.y * b.y, a.z * b.z, a.w * b.w);
}
// d = s - (o.x*i0 + o.y*i1 + o.z*i2 + o.w), componentwise over 4 pixels
__device__ __forceinline__ float4 dcompv(float4 s, float4 i0, float4 i1, float4 i2,
                                         float4 o) {
  float4 r;
  r.x = s.x - (o.x * i0.x + o.y * i1.x + o.z * i2.x + o.w);
  r.y = s.y - (o.x * i0.y + o.y * i1.y + o.z * i2.y + o.w);
  r.z = s.z - (o.x * i0.z + o.y * i1.z + o.z * i2.z + o.w);
  r.w = s.w - (o.x * i0.w + o.y * i1.w + o.z * i2.w + o.w);
  return r;
}
// 0.5-prescaled quadratic form (diag carries 0.5, offdiag carries 1.0)
__device__ __forceinline__ float quadv(float d0, float d1, float d2, float4 sA,
                                       float2 sB) {
  return sA.x * d0 * d0 + sA.y * d0 * d1 + sA.z * d0 * d2 + sA.w * d1 * d1 +
         sB.x * d1 * d2 + sB.y * d2 * d2;
}

// ------------------------------------------------------------------ 4x4 inverse
__device__ __forceinline__ void inv4(const float* Ain, float* out) {
  float a[4][8];
#pragma unroll
  for (int i = 0; i < 4; i++) {
#pragma unroll
    for (int j = 0; j < 4; j++) { a[i][j] = Ain[i * 4 + j]; a[i][4 + j] = (i == j) ? 1.f : 0.f; }
  }
#pragma unroll
  for (int c = 0; c < 4; c++) {
    float piv = 1.f / a[c][c];
#pragma unroll
    for (int j = 0; j < 8; j++) a[c][j] *= piv;
#pragma unroll
    for (int r = 0; r < 4; r++) {
      if (r != c) {
        float f = a[r][c];
#pragma unroll
        for (int j = 0; j < 8; j++) a[r][j] -= f * a[c][j];
      }
    }
  }
#pragma unroll
  for (int i = 0; i < 4; i++)
#pragma unroll
    for (int j = 0; j < 4; j++) out[i * 4 + j] = a[i][4 + j];
}

// ------------------------------------------------------------------ softmax (step 0)
__global__ __launch_bounds__(256) void k_softmax0(const float* __restrict__ pred,
                                                  float* __restrict__ gp) {
  int g = blockIdx.x * 256 + threadIdx.x;
  int u = g >> 14, p = g & (P_ - 1);
  const float* pr = pred + ((size_t)u * K_) * P_ + p;
  float l[K_];
  float mx = -1e30f;
#pragma unroll
  for (int k = 0; k < K_; k++) { l[k] = pr[(size_t)k * P_]; mx = fmaxf(mx, l[k]); }
  float s = 0.f;
#pragma unroll
  for (int k = 0; k < K_; k++) { l[k] = expf(l[k] - mx); s += l[k]; }
  float inv = 1.f / s;
  float* gw = gp + ((size_t)u * K_) * P_ + p;
#pragma unroll
  for (int k = 0; k < K_; k++) gw[(size_t)k * P_] = l[k] * inv + EPSF;
}

// ------------------------------------------------------------------ reduce1
// grid = B*K*2*NCR blocks x 256 thr; one (u, k, s-half, chunk) each; no barriers
// in the main loop. __launch_bounds__(256,2): VGPR cap 256 -> acc[58] stays in
// registers (round-4 counters showed 64-VGPR cap => ~90 MB scratch traffic).
__global__ __launch_bounds__(256, 2) void k_reduce1(const float* __restrict__ img,
                                                    const float* __restrict__ shf,
                                                    const float* __restrict__ gp,
                                                    float* __restrict__ p1) {
  __shared__ float red[58][33];
  int wg = swz8(blockIdx.x, B_ * K_ * 2 * NCR);
  int u = wg / (K_ * 2 * NCR);
  int r = wg % (K_ * 2 * NCR);
  int k = r / (2 * NCR), shalf = (r >> 2) & 1, ch = r & 3;
  int tid = threadIdx.x, lane = tid & 63, w = tid >> 6;

  const float* imgu = img + (size_t)u * CH * P_;
  const float* shfu = shf + ((size_t)u * S_ + shalf * 4) * CH * P_;
  const float* gpu = gp + (size_t)(u * K_ + k) * P_;

  float acc[58];
#pragma unroll
  for (int i = 0; i < 58; i++) acc[i] = 0.f;

#pragma unroll
  for (int it = 0; it < 4; it++) {
    int p = ch * 4096 + it * 1024 + tid * 4;
    float4 i0 = ld4(imgu + p);
    float4 i1 = ld4(imgu + P_ + p);
    float4 i2 = ld4(imgu + 2 * P_ + p);
    float4 g = ld4(gpu + p);
    float4 t0 = mul4(g, i0), t1 = mul4(g, i1), t2 = mul4(g, i2);
#pragma unroll
    for (int sa = 0; sa < 12; sa++) {
      float4 s = ld4(shfu + sa * P_ + p);
      acc[sa * 4 + 0] += dot4(s, t0);
      acc[sa * 4 + 1] += dot4(s, t1);
      acc[sa * 4 + 2] += dot4(s, t2);
      acc[sa * 4 + 3] += dot4(s, g);
    }
    if (shalf == 0) {  // block-uniform branch: M2 only from half 0
      acc[48] += dot4(i0, t0); acc[49] += dot4(i1, t0); acc[50] += dot4(i2, t0);
      acc[51] += sum4(t0);
      acc[52] += dot4(i1, t1); acc[53] += dot4(i2, t1); acc[54] += sum4(t1);
      acc[55] += dot4(i2, t2); acc[56] += sum4(t2);
      acc[57] += sum4(g);
    }
  }
#pragma unroll
  for (int j = 0; j < 58; j++) {
    float v = acc[j];
    v += __shfl_xor(v, 1, 64);
    v += __shfl_xor(v, 2, 64);
    v += __shfl_xor(v, 4, 64);
    acc[j] = v;
  }
  if ((lane & 7) == 0) {
    int col = w * 8 + (lane >> 3);
#pragma unroll
    for (int j = 0; j < 58; j++) red[j][col] = acc[j];
  }
  __syncthreads();
  if (tid < 58) {
    float s = 0.f;
#pragma unroll
    for (int c = 0; c < 32; c++) s += red[tid][c];
    if (shalf == 0) {
      int off = (tid < 48) ? tid : 96 + (tid - 48);
      p1[((size_t)(u * K_ + k) * NCR + ch) * NF1 + off] = s;
    } else if (tid < 48) {
      p1[((size_t)(u * K_ + k) * NCR + ch) * NF1 + 48 + tid] = s;
    }
  }
}

// ------------------------------------------------------------------ reduce2
__global__ __launch_bounds__(256, 2) void k_reduce2(const float* __restrict__ img,
                                                    const float* __restrict__ shf,
                                                    const float* __restrict__ gp,
                                                    const float* __restrict__ p1,
                                                    float* __restrict__ p2) {
  __shared__ float sum1[58];
  __shared__ float invA[16];
  __shared__ __align__(16) float opsS[48];
  __shared__ float nrmS[2];  // [0]=1/trace, [1]=1/sum(gp)
  __shared__ float red[24][33];
  int wg = swz8(blockIdx.x, B_ * K_ * 2 * NCR);
  int u = wg / (K_ * 2 * NCR);
  int r = wg % (K_ * 2 * NCR);
  int k = r / (2 * NCR), shalf = (r >> 2) & 1, ch = r & 3;
  int tid = threadIdx.x, lane = tid & 63, w = tid >> 6;

  if (tid < 58) {  // fixed-order chunk sums (only this block's half + M2)
    int idx = (tid < 48) ? (shalf * 48 + tid) : (96 + tid - 48);
    const float* src = p1 + (size_t)(u * K_ + k) * NCR * NF1 + idx;
    float s = 0.f;
#pragma unroll
    for (int c = 0; c < NCR; c++) s += src[c * NF1];
    sum1[tid] = s;
  }
  __syncthreads();
  if (tid == 0) {
    const float* m = &sum1[48];
    float tr = m[0] + m[4] + m[7] + m[9];
    float nrm = 1.f / tr;
    nrmS[0] = nrm;
    nrmS[1] = 1.f / m[9];
    const int sym[4][4] = {{0, 1, 2, 3}, {1, 4, 5, 6}, {2, 5, 7, 8}, {3, 6, 8, 9}};
    float A[16];
#pragma unroll
    for (int i = 0; i < 4; i++)
#pragma unroll
      for (int j = 0; j < 4; j++)
        A[i * 4 + j] = m[sym[i][j]] * nrm + ((i == j) ? EPSF : 0.f);
    inv4(A, invA);
  }
  __syncthreads();
  if (tid < 48) {
    int sa = tid >> 2, bc = tid & 3;
    float v = 0.f;
#pragma unroll
    for (int c = 0; c < 4; c++) v += sum1[sa * 4 + c] * invA[c * 4 + bc];
    opsS[tid] = v * nrmS[0];
  }
  __syncthreads();
  float pn = nrmS[1];

  const float* imgu = img + (size_t)u * CH * P_;
  const float* shfu = shf + ((size_t)u * S_ + shalf * 4) * CH * P_;
  const float* gpu = gp + (size_t)(u * K_ + k) * P_;

  float acc[24];
#pragma unroll
  for (int j = 0; j < 24; j++) acc[j] = 0.f;

#pragma unroll
  for (int it = 0; it < 4; it++) {
    int p = ch * 4096 + it * 1024 + tid * 4;
    float4 i0 = ld4(imgu + p);
    float4 i1 = ld4(imgu + P_ + p);
    float4 i2 = ld4(imgu + 2 * P_ + p);
    float4 g = ld4(gpu + p);
    float4 pp = make_float4(g.x * pn, g.y * pn, g.z * pn, g.w * pn);
#pragma unroll
    for (int sl = 0; sl < 4; sl++) {
      // wave-uniform LDS broadcasts (keeps register pressure low)
      float4 oA = ld4(&opsS[sl * 12 + 0]);
      float4 oB = ld4(&opsS[sl * 12 + 4]);
      float4 oC = ld4(&opsS[sl * 12 + 8]);
      float4 d0 = dcompv(ld4(shfu + (sl * 3 + 0) * P_ + p), i0, i1, i2, oA);
      float4 d1 = dcompv(ld4(shfu + (sl * 3 + 1) * P_ + p), i0, i1, i2, oB);
      float4 d2 = dcompv(ld4(shfu + (sl * 3 + 2) * P_ + p), i0, i1, i2, oC);
      float4 q0 = mul4(pp, d0), q1 = mul4(pp, d1), q2 = mul4(pp, d2);
      acc[sl * 6 + 0] += dot4(q0, d0);
      acc[sl * 6 + 1] += dot4(q0, d1);
      acc[sl * 6 + 2] += dot4(q0, d2);
      acc[sl * 6 + 3] += dot4(q1, d1);
      acc[sl * 6 + 4] += dot4(q1, d2);
      acc[sl * 6 + 5] += dot4(q2, d2);
    }
  }
#pragma unroll
  for (int j = 0; j < 24; j++) {
    float v = acc[j];
    v += __shfl_xor(v, 1, 64);
    v += __shfl_xor(v, 2, 64);
    v += __shfl_xor(v, 4, 64);
    acc[j] = v;
  }
  if ((lane & 7) == 0) {
    int col = w * 8 + (lane >> 3);
#pragma unroll
    for (int j = 0; j < 24; j++) red[j][col] = acc[j];
  }
  __syncthreads();
  if (tid < 24) {
    float s = 0.f;
#pragma unroll
    for (int c = 0; c < 32; c++) s += red[tid][c];
    p2[((size_t)(u * K_ + k) * NCR + ch) * NF2 + shalf * 24 + tid] = s;
  }
}

// ------------------------------------------------------------------ e-step (+ fused softmax)
// grid = B*NCE blocks x 768 thr = 12 waves = (6 k) x (2 s-halves); one 512-px chunk; 2 barriers.
template <int LAST>
__global__ __launch_bounds__(768, 3) void k_estep(const float* __restrict__ img,
                                                  const float* __restrict__ shf,
                                                  const float* __restrict__ pred,
                                                  const float* __restrict__ p1,
                                                  const float* __restrict__ p2,
                                                  float* __restrict__ out,
                                                  float* __restrict__ gp) {
  __shared__ float sum1[K_][NF1];
  __shared__ float sum2[K_][NF2];
  __shared__ float invA[K_][16];
  __shared__ float normL[K_];
  __shared__ __align__(16) float opsL[K_][96];
  __shared__ __align__(16) float sinvL[K_ * S_ * 8];  // padded stride 8
  __shared__ float ldetL[K_ * S_];
  __shared__ float ldhL[K_];
  __shared__ __align__(16) float qL[K_][512];
  __shared__ __align__(16) float gmL[K_][512];

  int wg = swz8(blockIdx.x, B_ * NCE);
  int u = wg >> 5, ch = wg & 31;
  int tid = threadIdx.x, lane = tid & 63, w = tid >> 6;
  int k = w >> 1, shalf = w & 1;

  for (int e = tid; e < K_ * NF1; e += 768) {
    int kk = e / NF1, i = e % NF1;
    const float* src = p1 + (size_t)(u * K_ + kk) * NCR * NF1 + i;
    float s = 0.f;
#pragma unroll
    for (int c = 0; c < NCR; c++) s += src[c * NF1];
    sum1[kk][i] = s;
  }
  for (int e = tid; e < K_ * NF2; e += 768) {
    int kk = e / NF2, j = e % NF2;
    const float* src = p2 + (size_t)(u * K_ + kk) * NCR * NF2 + j;
    float s = 0.f;
#pragma unroll
    for (int c = 0; c < NCR; c++) s += src[c * NF2];
    sum2[kk][j] = s;
  }
  __syncthreads();
  if (tid < K_) {
    const float* m = &sum1[tid][96];
    float tr = m[0] + m[4] + m[7] + m[9];
    float nrm = 1.f / tr;
    normL[tid] = nrm;
    const int sym[4][4] = {{0, 1, 2, 3}, {1, 4, 5, 6}, {2, 5, 7, 8}, {3, 6, 8, 9}};
    float A[16];
#pragma unroll
    for (int i = 0; i < 4; i++)
#pragma unroll
      for (int j = 0; j < 4; j++)
        A[i * 4 + j] = m[sym[i][j]] * nrm + ((i == j) ? EPSF : 0.f);
    inv4(A, invA[tid]);
  } else if (tid >= 64 && tid < 64 + K_ * S_) {
    int t2 = tid - 64;  // k*8+s
    const float* m = &sum2[t2 >> 3][(t2 & 7) * 6];
    float a = m[0] + EPSF, b = m[1], c = m[2];
    float d = m[3] + EPSF, e2 = m[4], f = m[5] + EPSF;
    float c00 = d * f - e2 * e2, c01 = c * e2 - b * f, c02 = b * e2 - c * d;
    float det = a * c00 + b * c01 + c * c02;
    float id = 1.f / det;
    sinvL[t2 * 8 + 0] = 0.5f * c00 * id;
    sinvL[t2 * 8 + 1] = c01 * id;
    sinvL[t2 * 8 + 2] = c02 * id;
    sinvL[t2 * 8 + 3] = 0.5f * (a * f - c * c) * id;
    sinvL[t2 * 8 + 4] = (c * b - a * e2) * id;
    sinvL[t2 * 8 + 5] = 0.5f * (a * d - b * b) * id;
    sinvL[t2 * 8 + 6] = 0.f;
    sinvL[t2 * 8 + 7] = 0.f;
    ldetL[t2] = logf(det);
  }
  __syncthreads();
  for (int e = tid; e < K_ * 96; e += 768) {
    int kk = e / 96, r = e % 96, sa = r >> 2, bc = r & 3;
    float v = 0.f;
#pragma unroll
    for (int c = 0; c < 4; c++) v += sum1[kk][sa * 4 + c] * invA[kk][c * 4 + bc];
    opsL[kk][r] = v * normL[kk];
  }
  if (tid < K_) {
    float s = 0.f;
#pragma unroll
    for (int si = 0; si < S_; si++) s += ldetL[tid * S_ + si];
    ldhL[tid] = 0.5f * s;
  }
  __syncthreads();

  const float* ob = &opsL[k][shalf * 48];
  const float* sb = &sinvL[(k * S_ + shalf * 4) * 8];
  float ldh = ldhL[k];

  const float* imgu = img + (size_t)u * CH * P_;
  const float* shfu = shf + ((size_t)u * S_ + shalf * 4) * CH * P_;

  int p0 = ch * 512 + lane * 4;  // iq=0; iq=1 is +256
  float4 i0a = ld4(imgu + p0),          i0b = ld4(imgu + p0 + 256);
  float4 i1a = ld4(imgu + P_ + p0),     i1b = ld4(imgu + P_ + p0 + 256);
  float4 i2a = ld4(imgu + 2 * P_ + p0), i2b = ld4(imgu + 2 * P_ + p0 + 256);
  float4 qa = make_float4(0.f, 0.f, 0.f, 0.f);
  float4 qb = make_float4(0.f, 0.f, 0.f, 0.f);
#pragma unroll
  for (int sl = 0; sl < 4; sl++) {
    float4 oA = ld4(ob + sl * 12 + 0);
    float4 oB = ld4(ob + sl * 12 + 4);
    float4 oC = ld4(ob + sl * 12 + 8);
    float4 sA = ld4(sb + sl * 8);
    float2 sB = *(const float2*)(sb + sl * 8 + 4);
    const float* s0 = shfu + (sl * 3 + 0) * P_;
    const float* s1 = shfu + (sl * 3 + 1) * P_;
    const float* s2 = shfu + (sl * 3 + 2) * P_;
    {
      float4 d0 = dcompv(ld4(s0 + p0), i0a, i1a, i2a, oA);
      float4 d1 = dcompv(ld4(s1 + p0), i0a, i1a, i2a, oB);
      float4 d2 = dcompv(ld4(s2 + p0), i0a, i1a, i2a, oC);
      qa.x += quadv(d0.x, d1.x, d2.x, sA, sB);
      qa.y += quadv(d0.y, d1.y, d2.y, sA, sB);
      qa.z += quadv(d0.z, d1.z, d2.z, sA, sB);
      qa.w += quadv(d0.w, d1.w, d2.w, sA, sB);
    }
    {
      float4 d0 = dcompv(ld4(s0 + p0 + 256), i0b, i1b, i2b, oA);
      float4 d1 = dcompv(ld4(s1 + p0 + 256), i0b, i1b, i2b, oB);
      float4 d2 = dcompv(ld4(s2 + p0 + 256), i0b, i1b, i2b, oC);
      qb.x += quadv(d0.x, d1.x, d2.x, sA, sB);
      qb.y += quadv(d0.y, d1.y, d2.y, sA, sB);
      qb.z += quadv(d0.z, d1.z, d2.z, sA, sB);
      qb.w += quadv(d0.w, d1.w, d2.w, sA, sB);
    }
  }
  int pxa = lane * 4, pxb = lane * 4 + 256;
  if (shalf == 1) {
    st4(&qL[k][pxa], qa);
    st4(&qL[k][pxb], qb);
  }
  __syncthreads();
  if (shalf == 0) {
    float* outu = out + (size_t)(u * K_ + k) * P_;
    float4 qha = ld4(&qL[k][pxa]);
    float4 qhb = ld4(&qL[k][pxb]);
    float4 g4a, g4b;
    g4a.x = -(qa.x + qha.x + ldh); g4a.y = -(qa.y + qha.y + ldh);
    g4a.z = -(qa.z + qha.z + ldh); g4a.w = -(qa.w + qha.w + ldh);
    g4b.x = -(qb.x + qhb.x + ldh); g4b.y = -(qb.y + qhb.y + ldh);
    g4b.z = -(qb.z + qhb.z + ldh); g4b.w = -(qb.w + qhb.w + ldh);
    st4(outu + ch * 512 + pxa, g4a);
    st4(outu + ch * 512 + pxb, g4b);
    if constexpr (!LAST) {
      st4(&gmL[k][pxa], g4a);
      st4(&gmL[k][pxb], g4b);
    }
  }
  if constexpr (!LAST) {
    __syncthreads();
    if (tid < 512) {
      int p = ch * 512 + tid;
      const float* predu = pred + (size_t)u * K_ * P_;
      float* gpu = gp + (size_t)u * K_ * P_;
      float l[K_];
      float mx = -1e30f;
#pragma unroll
      for (int k2 = 0; k2 < K_; k2++) {
        l[k2] = predu[(size_t)k2 * P_ + p] + gmL[k2][tid];
        mx = fmaxf(mx, l[k2]);
      }
      float ss = 0.f;
#pragma unroll
      for (int k2 = 0; k2 < K_; k2++) { l[k2] = expf(l[k2] - mx); ss += l[k2]; }
      float inv = 1.f / ss;
#pragma unroll
      for (int k2 = 0; k2 < K_; k2++) gpu[(size_t)k2 * P_ + p] = l[k2] * inv + EPSF;
    }
  }
}

// ------------------------------------------------------------------ launch
extern "C" void kernel_launch(void* const* d_in, const int* in_sizes, int n_in,
                              void* d_out, int out_size, void* d_ws, size_t ws_size,
                              hipStream_t stream) {
  const float* img = (const float*)d_in[0];   // [B,3,128,128]
  const float* shf = (const float*)d_in[1];   // [B,8,3,128,128]
  const float* pred = (const float*)d_in[2];  // [B,6,128,128]
  float* out = (float*)d_out;                 // [B,6,128,128]
  float* wsf = (float*)d_ws;
  float* gp = wsf;                               // B*K*P
  float* p1 = gp + (size_t)B_ * K_ * P_;         // B*K*NCR*NF1
  float* p2 = p1 + (size_t)B_ * K_ * NCR * NF1;  // B*K*NCR*NF2

  k_softmax0<<<(B_ * P_) / 256, 256, 0, stream>>>(pred, gp);
  for (int step = 0; step < 3; step++) {
    k_reduce1<<<B_ * K_ * 2 * NCR, 256, 0, stream>>>(img, shf, gp, p1);
    k_reduce2<<<B_ * K_ * 2 * NCR, 256, 0, stream>>>(img, shf, gp, p1, p2);
    if (step < 2)
      k_estep<0><<<B_ * NCE, 768, 0, stream>>>(img, shf, pred, p1, p2, out, gp);
    else
      k_estep<1><<<B_ * NCE, 768, 0, stream>>>(img, shf, pred, p1, p2, out, gp);
  }
}

// Round 6
// 144.159 us; speedup vs baseline: 3.9937x; 1.4120x over previous
//
#include <hip/hip_runtime.h>
#include <math.h>

#define EPSF 1.1920928955078125e-07f  // np.float32 eps

constexpr int B_ = 16, S_ = 8, CH = 3, K_ = 6;
constexpr int P_ = 128 * 128;  // pixels per image
constexpr int NCR = 4;         // moment chunks per image (4096 px each)
constexpr int NCE = 32;        // estep chunks per image (512 px each)
constexpr int NF = 160;        // p1 stride (154 moments padded): F 0..95, M2 96..105, Mss 106..153
constexpr int PW = 168;        // params stride: O 0..95, sinv 96..159 (8-stride), ldh 160

// bijective XCD swizzle (nwg % 8 == 0): same-u blocks land on one XCD
__device__ __forceinline__ int swz8(int bid, int nwg) {
  return (bid & 7) * (nwg >> 3) + (bid >> 3);
}
__device__ __forceinline__ float4 ld4(const float* p) { return *(const float4*)p; }
__device__ __forceinline__ void st4(float* p, float4 v) { *(float4*)p = v; }
__device__ __forceinline__ float dot4(float4 a, float4 b) {
  return a.x * b.x + a.y * b.y + a.z * b.z + a.w * b.w;
}
__device__ __forceinline__ float sum4(float4 a) { return a.x + a.y + a.z + a.w; }
__device__ __forceinline__ float4 mul4(float4 a, float4 b) {
  return make_float4(a.x * b.x, a.y * b.y, a.z * b.z, a.w * b.w);
}
__device__ __forceinline__ float4 dcompv(float4 s, float4 i0, float4 i1, float4 i2,
                                         float4 o) {
  float4 r;
  r.x = s.x - (o.x * i0.x + o.y * i1.x + o.z * i2.x + o.w);
  r.y = s.y - (o.x * i0.y + o.y * i1.y + o.z * i2.y + o.w);
  r.z = s.z - (o.x * i0.z + o.y * i1.z + o.z * i2.z + o.w);
  r.w = s.w - (o.x * i0.w + o.y * i1.w + o.z * i2.w + o.w);
  return r;
}
// 0.5-prescaled quadratic form (diag carries 0.5, offdiag carries 1.0)
__device__ __forceinline__ float quadv(float d0, float d1, float d2, float4 sA,
                                       float2 sB) {
  return sA.x * d0 * d0 + sA.y * d0 * d1 + sA.z * d0 * d2 + sA.w * d1 * d1 +
         sB.x * d1 * d2 + sB.y * d2 * d2;
}

// ------------------------------------------------------------------ 4x4 inverse
__device__ __forceinline__ void inv4(const float* Ain, float* out) {
  float a[4][8];
#pragma unroll
  for (int i = 0; i < 4; i++) {
#pragma unroll
    for (int j = 0; j < 4; j++) { a[i][j] = Ain[i * 4 + j]; a[i][4 + j] = (i == j) ? 1.f : 0.f; }
  }
#pragma unroll
  for (int c = 0; c < 4; c++) {
    float piv = 1.f / a[c][c];
#pragma unroll
    for (int j = 0; j < 8; j++) a[c][j] *= piv;
#pragma unroll
    for (int r = 0; r < 4; r++) {
      if (r != c) {
        float f = a[r][c];
#pragma unroll
        for (int j = 0; j < 8; j++) a[r][j] -= f * a[c][j];
      }
    }
  }
#pragma unroll
  for (int i = 0; i < 4; i++)
#pragma unroll
    for (int j = 0; j < 4; j++) out[i * 4 + j] = a[i][4 + j];
}

// ------------------------------------------------------------------ softmax (step 0)
__global__ __launch_bounds__(256) void k_softmax0(const float* __restrict__ pred,
                                                  float* __restrict__ gp) {
  int g = blockIdx.x * 256 + threadIdx.x;
  int u = g >> 14, p = g & (P_ - 1);
  const float* pr = pred + ((size_t)u * K_) * P_ + p;
  float l[K_];
  float mx = -1e30f;
#pragma unroll
  for (int k = 0; k < K_; k++) { l[k] = pr[(size_t)k * P_]; mx = fmaxf(mx, l[k]); }
  float s = 0.f;
#pragma unroll
  for (int k = 0; k < K_; k++) { l[k] = expf(l[k] - mx); s += l[k]; }
  float inv = 1.f / s;
  float* gw = gp + ((size_t)u * K_) * P_ + p;
#pragma unroll
  for (int k = 0; k < K_; k++) gw[(size_t)k * P_] = l[k] * inv + EPSF;
}

// ------------------------------------------------------------------ moments
// grid = B*K*4*NCR blocks x 256 thr; one (u, k, s-quarter(2 s), chunk) each.
// Accumulates F (24), Mss (12), and (quarter 0 only) M2 (10) = 46 registers.
// launch_bounds(256,1): allocator must not cut below the live set (spill history:
// r4 VGPR=64/90MB scratch, r5 VGPR=128/86MB scratch).
__global__ __launch_bounds__(256, 1) void k_moments(const float* __restrict__ img,
                                                    const float* __restrict__ shf,
                                                    const float* __restrict__ gp,
                                                    float* __restrict__ p1) {
  __shared__ float red[46][33];
  int wg = swz8(blockIdx.x, B_ * K_ * 4 * NCR);
  int u = wg / 96;
  int r = wg % 96;
  int k = r >> 4, sq = (r >> 2) & 3, ch = r & 3;
  int tid = threadIdx.x, lane = tid & 63, w = tid >> 6;

  const float* imgu = img + (size_t)u * CH * P_;
  const float* shfu = shf + ((size_t)u * S_ + sq * 2) * CH * P_;
  const float* gpu = gp + (size_t)(u * K_ + k) * P_;

  float acc[46];
#pragma unroll
  for (int i = 0; i < 46; i++) acc[i] = 0.f;

#pragma unroll
  for (int it = 0; it < 4; it++) {
    int p = ch * 4096 + it * 1024 + tid * 4;
    float4 i0 = ld4(imgu + p);
    float4 i1 = ld4(imgu + P_ + p);
    float4 i2 = ld4(imgu + 2 * P_ + p);
    float4 g = ld4(gpu + p);
    float4 t0 = mul4(g, i0), t1 = mul4(g, i1), t2 = mul4(g, i2);
#pragma unroll
    for (int ls = 0; ls < 2; ls++) {
      float4 s0 = ld4(shfu + (ls * 3 + 0) * P_ + p);
      float4 s1 = ld4(shfu + (ls * 3 + 1) * P_ + p);
      float4 s2 = ld4(shfu + (ls * 3 + 2) * P_ + p);
      int fb = ls * 12;
      acc[fb + 0] += dot4(s0, t0); acc[fb + 1] += dot4(s0, t1);
      acc[fb + 2] += dot4(s0, t2); acc[fb + 3] += dot4(s0, g);
      acc[fb + 4] += dot4(s1, t0); acc[fb + 5] += dot4(s1, t1);
      acc[fb + 6] += dot4(s1, t2); acc[fb + 7] += dot4(s1, g);
      acc[fb + 8] += dot4(s2, t0); acc[fb + 9] += dot4(s2, t1);
      acc[fb + 10] += dot4(s2, t2); acc[fb + 11] += dot4(s2, g);
      // Mss sym: (00)(01)(02)(11)(12)(22), gp-weighted
      float4 gs0 = mul4(g, s0), gs1 = mul4(g, s1), gs2 = mul4(g, s2);
      int mb = 24 + ls * 6;
      acc[mb + 0] += dot4(gs0, s0); acc[mb + 1] += dot4(gs0, s1);
      acc[mb + 2] += dot4(gs0, s2); acc[mb + 3] += dot4(gs1, s1);
      acc[mb + 4] += dot4(gs1, s2); acc[mb + 5] += dot4(gs2, s2);
    }
    if (sq == 0) {  // block-uniform: M2 only from quarter 0
      acc[36] += dot4(i0, t0); acc[37] += dot4(i1, t0); acc[38] += dot4(i2, t0);
      acc[39] += sum4(t0);
      acc[40] += dot4(i1, t1); acc[41] += dot4(i2, t1); acc[42] += sum4(t1);
      acc[43] += dot4(i2, t2); acc[44] += sum4(t2);
      acc[45] += sum4(g);
    }
  }
#pragma unroll
  for (int j = 0; j < 46; j++) {
    float v = acc[j];
    v += __shfl_xor(v, 1, 64);
    v += __shfl_xor(v, 2, 64);
    v += __shfl_xor(v, 4, 64);
    acc[j] = v;
  }
  if ((lane & 7) == 0) {
    int col = w * 8 + (lane >> 3);
#pragma unroll
    for (int j = 0; j < 46; j++) red[j][col] = acc[j];
  }
  __syncthreads();
  if (tid < 46 && (tid < 36 || sq == 0)) {
    float s = 0.f;
#pragma unroll
    for (int c = 0; c < 32; c++) s += red[tid][c];
    int off = (tid < 24) ? (sq * 24 + tid)
                         : (tid < 36 ? (106 + sq * 12 + tid - 24) : (96 + tid - 36));
    p1[((size_t)(u * K_ + k) * NCR + ch) * NF + off] = s;
  }
}

// ------------------------------------------------------------------ solve (per u)
// O_s = norm * F_s * inv(norm*M2 + eps I)
// sigma_s = pn*(Mss_s - F_s O_s^T - O_s F_s^T + O_s M2 O_s^T) + eps I   (exact)
__global__ __launch_bounds__(256) void k_solve(const float* __restrict__ p1,
                                               float* __restrict__ params) {
  __shared__ float sumL[K_][154];
  __shared__ float invAL[K_][16];
  __shared__ float OL[K_][96];
  __shared__ float normL[K_], pnL[K_];
  __shared__ float ldetL[K_ * S_];
  int u = blockIdx.x;
  int tid = threadIdx.x;

  for (int e = tid; e < K_ * 154; e += 256) {
    int k = e / 154, i = e % 154;
    const float* src = p1 + (size_t)(u * K_ + k) * NCR * NF + i;
    float s = 0.f;
#pragma unroll
    for (int c = 0; c < NCR; c++) s += src[c * NF];
    sumL[k][i] = s;
  }
  __syncthreads();
  if (tid < K_) {
    const float* m = &sumL[tid][96];
    float tr = m[0] + m[4] + m[7] + m[9];
    float nrm = 1.f / tr;
    normL[tid] = nrm;
    pnL[tid] = 1.f / m[9];
    const int sym[4][4] = {{0, 1, 2, 3}, {1, 4, 5, 6}, {2, 5, 7, 8}, {3, 6, 8, 9}};
    float A[16];
#pragma unroll
    for (int i = 0; i < 4; i++)
#pragma unroll
      for (int j = 0; j < 4; j++)
        A[i * 4 + j] = m[sym[i][j]] * nrm + ((i == j) ? EPSF : 0.f);
    inv4(A, invAL[tid]);
  }
  __syncthreads();
  for (int e = tid; e < K_ * 96; e += 256) {
    int k = e / 96, r = e % 96, sa = r >> 2, bc = r & 3;
    float v = 0.f;
#pragma unroll
    for (int c = 0; c < 4; c++) v += sumL[k][sa * 4 + c] * invAL[k][c * 4 + bc];
    v *= normL[k];
    OL[k][r] = v;
    params[(size_t)(u * K_ + k) * PW + r] = v;
  }
  __syncthreads();
  if (tid < K_ * S_) {
    int k = tid >> 3, s = tid & 7;
    const float* F = &sumL[k][s * 12];   // F[a*4+c]
    const float* O = &OL[k][s * 12];     // O[a*4+c]
    const float* M2 = &sumL[k][96];      // 10 sym
    const float* Ms = &sumL[k][106 + s * 6];
    float pn = pnL[k];
    const int sym[4][4] = {{0, 1, 2, 3}, {1, 4, 5, 6}, {2, 5, 7, 8}, {3, 6, 8, 9}};
    float FO[9];
#pragma unroll
    for (int a = 0; a < 3; a++)
#pragma unroll
      for (int b = 0; b < 3; b++) {
        float v = 0.f;
#pragma unroll
        for (int c = 0; c < 4; c++) v += F[a * 4 + c] * O[b * 4 + c];
        FO[a * 3 + b] = v;
      }
    float W[12];
#pragma unroll
    for (int a = 0; a < 3; a++)
#pragma unroll
      for (int c = 0; c < 4; c++) {
        float v = 0.f;
#pragma unroll
        for (int d = 0; d < 4; d++) v += O[a * 4 + d] * M2[sym[d][c]];
        W[a * 4 + c] = v;
      }
    float OMO[6];
    {
      const int pa[6] = {0, 0, 0, 1, 1, 2}, pb[6] = {0, 1, 2, 1, 2, 2};
#pragma unroll
      for (int t = 0; t < 6; t++) {
        float v = 0.f;
#pragma unroll
        for (int c = 0; c < 4; c++) v += W[pa[t] * 4 + c] * O[pb[t] * 4 + c];
        OMO[t] = v;
      }
    }
    float a = pn * (Ms[0] - 2.f * FO[0] + OMO[0]) + EPSF;
    float b = pn * (Ms[1] - FO[1] - FO[3] + OMO[1]);
    float c = pn * (Ms[2] - FO[2] - FO[6] + OMO[2]);
    float d = pn * (Ms[3] - 2.f * FO[4] + OMO[3]) + EPSF;
    float e = pn * (Ms[4] - FO[5] - FO[7] + OMO[4]);
    float f = pn * (Ms[5] - 2.f * FO[8] + OMO[5]) + EPSF;
    float c00 = d * f - e * e, c01 = c * e - b * f, c02 = b * e - c * d;
    float det = a * c00 + b * c01 + c * c02;
    float id = 1.f / det;
    float* ps = params + (size_t)(u * K_ + k) * PW + 96 + s * 8;
    ps[0] = 0.5f * c00 * id;
    ps[1] = c01 * id;
    ps[2] = c02 * id;
    ps[3] = 0.5f * (a * f - c * c) * id;
    ps[4] = (c * b - a * e) * id;
    ps[5] = 0.5f * (a * d - b * b) * id;
    ldetL[tid] = logf(det);
  }
  __syncthreads();
  if (tid < K_) {
    float s = 0.f;
#pragma unroll
    for (int si = 0; si < S_; si++) s += ldetL[tid * S_ + si];
    params[(size_t)(u * K_ + tid) * PW + 160] = 0.5f * s;
  }
}

// ------------------------------------------------------------------ e-step (+ fused softmax)
// grid = B*NCE blocks x 768 thr = 12 waves = (6 k) x (2 s-halves); one 512-px chunk.
template <int LAST>
__global__ __launch_bounds__(768, 3) void k_estep(const float* __restrict__ img,
                                                  const float* __restrict__ shf,
                                                  const float* __restrict__ pred,
                                                  const float* __restrict__ params,
                                                  float* __restrict__ out,
                                                  float* __restrict__ gp) {
  __shared__ __align__(16) float pL[K_][PW];
  __shared__ __align__(16) float qL[K_][512];
  __shared__ __align__(16) float gmL[K_][512];

  int wg = swz8(blockIdx.x, B_ * NCE);
  int u = wg >> 5, ch = wg & 31;
  int tid = threadIdx.x, lane = tid & 63, w = tid >> 6;
  int k = w >> 1, shalf = w & 1;

  for (int e = tid; e < K_ * PW; e += 768)
    pL[e / PW][e % PW] = params[(size_t)u * K_ * PW + e];
  __syncthreads();

  const float* ob = &pL[k][shalf * 48];
  const float* sb = &pL[k][96 + shalf * 32];
  float ldh = pL[k][160];

  const float* imgu = img + (size_t)u * CH * P_;
  const float* shfu = shf + ((size_t)u * S_ + shalf * 4) * CH * P_;

  int p0 = ch * 512 + lane * 4;  // iq=0; iq=1 is +256
  float4 i0a = ld4(imgu + p0),          i0b = ld4(imgu + p0 + 256);
  float4 i1a = ld4(imgu + P_ + p0),     i1b = ld4(imgu + P_ + p0 + 256);
  float4 i2a = ld4(imgu + 2 * P_ + p0), i2b = ld4(imgu + 2 * P_ + p0 + 256);
  float4 qa = make_float4(0.f, 0.f, 0.f, 0.f);
  float4 qb = make_float4(0.f, 0.f, 0.f, 0.f);
#pragma unroll
  for (int sl = 0; sl < 4; sl++) {
    float4 oA = ld4(ob + sl * 12 + 0);
    float4 oB = ld4(ob + sl * 12 + 4);
    float4 oC = ld4(ob + sl * 12 + 8);
    float4 sA = ld4(sb + sl * 8);
    float2 sB = *(const float2*)(sb + sl * 8 + 4);
    const float* s0 = shfu + (sl * 3 + 0) * P_;
    const float* s1 = shfu + (sl * 3 + 1) * P_;
    const float* s2 = shfu + (sl * 3 + 2) * P_;
    {
      float4 d0 = dcompv(ld4(s0 + p0), i0a, i1a, i2a, oA);
      float4 d1 = dcompv(ld4(s1 + p0), i0a, i1a, i2a, oB);
      float4 d2 = dcompv(ld4(s2 + p0), i0a, i1a, i2a, oC);
      qa.x += quadv(d0.x, d1.x, d2.x, sA, sB);
      qa.y += quadv(d0.y, d1.y, d2.y, sA, sB);
      qa.z += quadv(d0.z, d1.z, d2.z, sA, sB);
      qa.w += quadv(d0.w, d1.w, d2.w, sA, sB);
    }
    {
      float4 d0 = dcompv(ld4(s0 + p0 + 256), i0b, i1b, i2b, oA);
      float4 d1 = dcompv(ld4(s1 + p0 + 256), i0b, i1b, i2b, oB);
      float4 d2 = dcompv(ld4(s2 + p0 + 256), i0b, i1b, i2b, oC);
      qb.x += quadv(d0.x, d1.x, d2.x, sA, sB);
      qb.y += quadv(d0.y, d1.y, d2.y, sA, sB);
      qb.z += quadv(d0.z, d1.z, d2.z, sA, sB);
      qb.w += quadv(d0.w, d1.w, d2.w, sA, sB);
    }
  }
  int pxa = lane * 4, pxb = lane * 4 + 256;
  if (shalf == 1) {
    st4(&qL[k][pxa], qa);
    st4(&qL[k][pxb], qb);
  }
  __syncthreads();
  if (shalf == 0) {
    float* outu = out + (size_t)(u * K_ + k) * P_;
    float4 qha = ld4(&qL[k][pxa]);
    float4 qhb = ld4(&qL[k][pxb]);
    float4 g4a, g4b;
    g4a.x = -(qa.x + qha.x + ldh); g4a.y = -(qa.y + qha.y + ldh);
    g4a.z = -(qa.z + qha.z + ldh); g4a.w = -(qa.w + qha.w + ldh);
    g4b.x = -(qb.x + qhb.x + ldh); g4b.y = -(qb.y + qhb.y + ldh);
    g4b.z = -(qb.z + qhb.z + ldh); g4b.w = -(qb.w + qhb.w + ldh);
    st4(outu + ch * 512 + pxa, g4a);
    st4(outu + ch * 512 + pxb, g4b);
    if constexpr (!LAST) {
      st4(&gmL[k][pxa], g4a);
      st4(&gmL[k][pxb], g4b);
    }
  }
  if constexpr (!LAST) {
    __syncthreads();
    if (tid < 512) {
      int p = ch * 512 + tid;
      const float* predu = pred + (size_t)u * K_ * P_;
      float* gpu = gp + (size_t)u * K_ * P_;
      float l[K_];
      float mx = -1e30f;
#pragma unroll
      for (int k2 = 0; k2 < K_; k2++) {
        l[k2] = predu[(size_t)k2 * P_ + p] + gmL[k2][tid];
        mx = fmaxf(mx, l[k2]);
      }
      float ss = 0.f;
#pragma unroll
      for (int k2 = 0; k2 < K_; k2++) { l[k2] = expf(l[k2] - mx); ss += l[k2]; }
      float inv = 1.f / ss;
#pragma unroll
      for (int k2 = 0; k2 < K_; k2++) gpu[(size_t)k2 * P_ + p] = l[k2] * inv + EPSF;
    }
  }
}

// ------------------------------------------------------------------ launch
extern "C" void kernel_launch(void* const* d_in, const int* in_sizes, int n_in,
                              void* d_out, int out_size, void* d_ws, size_t ws_size,
                              hipStream_t stream) {
  const float* img = (const float*)d_in[0];   // [B,3,128,128]
  const float* shf = (const float*)d_in[1];   // [B,8,3,128,128]
  const float* pred = (const float*)d_in[2];  // [B,6,128,128]
  float* out = (float*)d_out;                 // [B,6,128,128]
  float* wsf = (float*)d_ws;
  float* gp = wsf;                                // B*K*P
  float* p1 = gp + (size_t)B_ * K_ * P_;          // B*K*NCR*NF
  float* params = p1 + (size_t)B_ * K_ * NCR * NF;  // B*K*PW

  k_softmax0<<<(B_ * P_) / 256, 256, 0, stream>>>(pred, gp);
  for (int step = 0; step < 3; step++) {
    k_moments<<<B_ * K_ * 4 * NCR, 256, 0, stream>>>(img, shf, gp, p1);
    k_solve<<<B_, 256, 0, stream>>>(p1, params);
    if (step < 2)
      k_estep<0><<<B_ * NCE, 768, 0, stream>>>(img, shf, pred, params, out, gp);
    else
      k_estep<1><<<B_ * NCE, 768, 0, stream>>>(img, shf, pred, params, out, gp);
  }
}